// Round 11
// baseline (551.906 us; speedup 1.0000x reference)
//
#include <hip/hip_runtime.h>
#include <math.h>

#define NB   1024
#define TSEQ 32
#define DM   256
#define DF   158
#define GDIM 63
#define XROW 221

typedef unsigned short u16;
typedef __attribute__((ext_vector_type(8))) __bf16 bf16x8;
typedef __attribute__((ext_vector_type(4))) float f32x4;
#define MFMA16(a,b,c) __builtin_amdgcn_mfma_f32_16x16x32_bf16(a,b,c,0,0,0)

#define MODE_PROJ 0
#define MODE_QKVT 1
#define MODE_QKVS 2
#define MODE_TEMP 3

__device__ __forceinline__ u16 f2bf(float f){
  union { float f; unsigned int u; } c; c.f = f;
  unsigned int u = c.u;
  u += 0x7fffu + ((u >> 16) & 1u);   // round-to-nearest-even
  return (u16)(u >> 16);
}

// truncating bf16 (for P in attention: bias cancels between O and l)
__device__ __forceinline__ u16 f2bf_t(float f){
  union { float f; unsigned int u; } c; c.f = f;
  return (u16)(c.u >> 16);
}

// async 16B global->LDS DMA: LDS dest = wave-uniform base + lane*16.
__device__ __forceinline__ void gl2lds16(const u16* g, u16* lds_wave_base, int lane){
#if __has_builtin(__builtin_amdgcn_global_load_lds)
  __builtin_amdgcn_global_load_lds(
      (const __attribute__((address_space(1))) unsigned int*)g,
      (__attribute__((address_space(3))) unsigned int*)lds_wave_base,
      16, 0, 0);
#else
  *reinterpret_cast<uint4*>(lds_wave_base + lane * 8) =
      *reinterpret_cast<const uint4*>(g);
#endif
}

// LayerNorm over last dim (256) for a 32-row tile in LDS. 8 threads/row.
__device__ __forceinline__ void ln_rows32(float* buf, int stride,
                                          const float* __restrict__ g,
                                          const float* __restrict__ b,
                                          int tid)
{
  const int s = tid >> 3, j = tid & 7;
  float* row = buf + s * stride;
  float sum = 0.f, sq = 0.f;
  #pragma unroll
  for (int k = 0; k < DM; k += 8){
    float v = row[k + j];
    sum += v; sq += v * v;
  }
  #pragma unroll
  for (int o = 1; o < 8; o <<= 1){
    sum += __shfl_xor(sum, o);
    sq  += __shfl_xor(sq, o);
  }
  const float mu  = sum * (1.f / DM);
  const float var = sq * (1.f / DM) - mu * mu;
  const float rs  = rsqrtf(var + 1e-5f);
  #pragma unroll
  for (int k = 0; k < DM; k += 8){
    float v = row[k + j];
    row[k + j] = (v - mu) * rs * g[k + j] + b[k + j];
  }
}

// ---------------- weight conversion (fp32 -> bf16, packed) ----------------
#define WB_TOT 770048

__global__ __launch_bounds__(256) void kConvAll(
    const float* __restrict__ tq, const float* __restrict__ tk, const float* __restrict__ tv,
    const float* __restrict__ sq, const float* __restrict__ sk, const float* __restrict__ sv,
    const float* __restrict__ tf1, const float* __restrict__ tf2,
    const float* __restrict__ sf1, const float* __restrict__ sf2,
    const float* __restrict__ tw, const float* __restrict__ pw,
    u16* __restrict__ WB)
{
  int i = blockIdx.x * 256 + threadIdx.x;
  if (i >= WB_TOT) return;
  if (i < 720896){
    int j = i >> 16, o = i & 65535;
    const float* s;
    switch (j){
      case 0: s = tq; break;  case 1: s = tk; break;  case 2: s = tv; break;
      case 3: s = sq; break;  case 4: s = sk; break;  case 5: s = sv; break;
      case 6: s = tf1; break; case 7: s = tf2; break;
      case 8: s = sf1; break; case 9: s = sf2; break;
      default: s = tw; break;
    }
    WB[i] = f2bf(s[o]);
  } else {
    int k = i - 720896;
    int row = k / 192, col = k - row * 192;
    WB[i] = (col < DF) ? f2bf(pw[row * DF + col]) : (u16)0;
  }
}

// ---------------- gate + gated src (bf16, K padded to 192) ----------------

__global__ __launch_bounds__(256) void kGateSrc(
    const float* __restrict__ x,
    const float* __restrict__ gate_w, const float* __restrict__ gate_b,
    u16* __restrict__ SRC)
{
  __shared__ float s_gate[DF];
  __shared__ float s_gi[GDIM];
  const int tid = threadIdx.x;
  const int n = blockIdx.x;

  if (tid < GDIM) s_gi[tid] = x[(n * TSEQ + (TSEQ - 1)) * XROW + DF + tid];
  __syncthreads();
  float logit = 0.f;
  if (tid < DF){
    logit = gate_b[tid];
    const float* __restrict__ wr = gate_w + tid * GDIM;
    for (int g = 0; g < GDIM; ++g) logit += s_gi[g] * wr[g];
    logit *= 0.2f;
    s_gate[tid] = logit;
  }
  __syncthreads();
  {
    float mx = -1e30f;
    for (int f = 0; f < DF; ++f) mx = fmaxf(mx, s_gate[f]);
    float sm = 0.f;
    for (int f = 0; f < DF; ++f) sm += __expf(s_gate[f] - mx);
    __syncthreads();
    if (tid < DF) s_gate[tid] = (float)DF * __expf(logit - mx) / sm;
  }
  __syncthreads();

  for (int e = tid; e < TSEQ * 192; e += 256){
    int t = e / 192, f = e - t * 192;
    float v = 0.f;
    if (f < DF) v = x[(n * TSEQ + t) * XROW + f] * s_gate[f];
    SRC[(size_t)(n * TSEQ + t) * 192 + f] = f2bf(v);
  }
}

// ---------------- bf16 MFMA GEMM: C = A[M x K] @ B[N x K]^T ----------------
// 512 threads, 128(M) x 256(N) block tile, 8 waves in 2x4, 64x64 wave tiles.
// MODE_QKVS uses t-major row-block mapping (full-line V^T scatter writes).

__global__ __launch_bounds__(512) void gemm_bf16(
    const u16* __restrict__ A, const u16* __restrict__ B,
    const int K, const int mode,
    const float* __restrict__ bias,
    float* __restrict__ outf,
    u16* __restrict__ ob0, u16* __restrict__ ob1, u16* __restrict__ ob2)
{
  __shared__ alignas(16) u16 sA[128 * 64];   // 16 KB
  __shared__ alignas(16) u16 sB[256 * 64];   // 32 KB
  const int tid = threadIdx.x;
  const int wv = tid >> 6, lane = tid & 63;
  const int wr = wv >> 2, wc = wv & 3;
  const int quad = lane >> 4, lc = lane & 15;
  const int n0 = blockIdx.y * 256;
  const bool tmaj = (mode == MODE_QKVS);
  const int tt = tmaj ? (blockIdx.x & 31) : 0;
  const int nb = tmaj ? (blockIdx.x >> 5) : 0;
  const int m0 = tmaj ? 0 : blockIdx.x * 128;

  f32x4 acc[4][4];
  #pragma unroll
  for (int i = 0; i < 4; ++i)
    #pragma unroll
    for (int j = 0; j < 4; ++j) acc[i][j] = (f32x4){0.f,0.f,0.f,0.f};

  for (int kt = 0; kt < K; kt += 64){
    __syncthreads();
    #pragma unroll
    for (int j = 0; j < 2; ++j){
      int cA = wv * 2 + j;
      int row = cA * 8 + (lane >> 3), blk = lane & 7;
      int arow = tmaj ? ((nb * 128 + row) * 32 + tt) : (m0 + row);
      gl2lds16(A + (size_t)arow * K + kt + ((blk ^ (row & 7)) * 8),
               &sA[cA * 512], lane);
    }
    #pragma unroll
    for (int j = 0; j < 4; ++j){
      int cB = wv * 4 + j;
      int row = cB * 8 + (lane >> 3), blk = lane & 7;
      gl2lds16(B + (size_t)(n0 + row) * K + kt + ((blk ^ (row & 7)) * 8),
               &sB[cB * 512], lane);
    }
    __syncthreads();
    #pragma unroll
    for (int kc = 0; kc < 2; ++kc){
      const int sw = ((kc * 4 + quad) ^ (lc & 7)) * 8;
      bf16x8 a[4], b[4];
      #pragma unroll
      for (int i = 0; i < 4; ++i){
        a[i] = *reinterpret_cast<const bf16x8*>(&sA[(wr * 64 + i * 16 + lc) * 64 + sw]);
        b[i] = *reinterpret_cast<const bf16x8*>(&sB[(wc * 64 + i * 16 + lc) * 64 + sw]);
      }
      #pragma unroll
      for (int i = 0; i < 4; ++i)
        #pragma unroll
        for (int j = 0; j < 4; ++j)
          acc[i][j] = MFMA16(a[i], b[j], acc[i][j]);
    }
  }

  // -------- epilogue --------
  const int rb = wr * 64 + quad * 4;
  const int cb = wc * 64 + lc;

  if (mode == MODE_PROJ){
    #pragma unroll
    for (int i = 0; i < 4; ++i)
      #pragma unroll
      for (int r = 0; r < 4; ++r){
        int row = m0 + rb + i * 16 + r;
        float ft = (float)(row & 31);
        #pragma unroll
        for (int j = 0; j < 4; ++j){
          int col = n0 + cb + j * 16;
          float div = __expf((float)(col & ~1) * -0.035977892f);
          float ang = ft * div;
          float pe = (col & 1) ? __cosf(ang) : __sinf(ang);
          outf[(size_t)row * 256 + col] = acc[i][j][r] + bias[col] + pe;
        }
      }
  } else if (mode == MODE_QKVT){
    #pragma unroll
    for (int i = 0; i < 4; ++i)
      #pragma unroll
      for (int r = 0; r < 4; ++r){
        int row = m0 + rb + i * 16 + r;
        #pragma unroll
        for (int j = 0; j < 4; ++j){
          int col = n0 + cb + j * 16;
          int sel = col >> 8, c = col & 255;
          u16 v = f2bf(acc[i][j][r]);
          if (sel == 0)      ob0[(size_t)row * 256 + c] = v;
          else if (sel == 1) ob1[(size_t)row * 256 + c] = v;
          else {
            int h = c >> 6, dd = c & 63;
            ob2[(((size_t)(row >> 5) * 4 + h) * 64 + dd) * 32 + (row & 31)] = v;
          }
        }
      }
  } else if (mode == MODE_QKVS){
    #pragma unroll
    for (int i = 0; i < 4; ++i)
      #pragma unroll
      for (int r = 0; r < 4; ++r){
        int rl = rb + i * 16 + r;
        int n = nb * 128 + rl;
        #pragma unroll
        for (int j = 0; j < 4; ++j){
          int col = n0 + cb + j * 16;
          int sel = col >> 8, c = col & 255;
          u16 v = f2bf(acc[i][j][r]);
          if (sel == 0)      ob0[((size_t)tt * NB + n) * 256 + c] = v;
          else if (sel == 1) ob1[((size_t)tt * NB + n) * 256 + c] = v;
          else {
            int h = c >> 7, dd = c & 127;
            ob2[(((size_t)tt * 2 + h) * 128 + dd) * NB + n] = v;
          }
        }
      }
  } else { // MODE_TEMP
    #pragma unroll
    for (int i = 0; i < 4; ++i)
      #pragma unroll
      for (int r = 0; r < 4; ++r){
        int row = m0 + rb + i * 16 + r;
        #pragma unroll
        for (int j = 0; j < 4; ++j){
          int col = n0 + cb + j * 16;
          outf[(size_t)row * 256 + col] = acc[i][j][r];
        }
      }
  }
}

// ---------------- generic LayerNorm: fp32 in -> bf16 + fp32 out ----------------

__global__ __launch_bounds__(256) void kLN(
    const float* __restrict__ X, const float* __restrict__ g,
    const float* __restrict__ b,
    u16* __restrict__ Xb, float* __restrict__ Xf)
{
  __shared__ float s_z[32 * DM];
  const int tid = threadIdx.x;
  const size_t base = (size_t)blockIdx.x * (32 * DM);
  for (int e = tid; e < 32 * DM; e += 256) s_z[e] = X[base + e];
  __syncthreads();
  ln_rows32(s_z, DM, g, b, tid);
  __syncthreads();
  for (int e = tid; e < 32 * DM; e += 256){
    float v = s_z[e];
    Xb[base + e] = f2bf(v);
    Xf[base + e] = v;
  }
}

// ---------------- fused LN2 + FFN ----------------

__global__ __launch_bounds__(512) void kFFN(
    const float* __restrict__ X,
    const float* __restrict__ lg, const float* __restrict__ lb,
    const u16* __restrict__ w1, const float* __restrict__ b1,
    const u16* __restrict__ w2, const float* __restrict__ b2,
    float* __restrict__ outf, u16* __restrict__ obdual)
{
  __shared__ alignas(16) u16 sAB[24576];
  __shared__ alignas(16) u16 s_h1[128 * 256];
  __shared__ float s_mu[128], s_rs[128];
  __shared__ float s_lg[256], s_lb[256], s_b1[256], s_b2[256];

  const int tid = threadIdx.x;
  const int wv = tid >> 6, lane = tid & 63;
  const int quad = lane >> 4, lc = lane & 15;
  const int m0 = blockIdx.x * 128;
  const int m0w = (wv >> 1) * 32;
  const int n0w = (wv & 1) * 128;
  u16* sA = sAB;
  u16* sB = sAB + 8192;

  if (tid < 256){
    s_lg[tid] = lg[tid]; s_lb[tid] = lb[tid];
    s_b1[tid] = b1[tid]; s_b2[tid] = b2[tid];
  }

  {
    const int row = tid >> 2, j = tid & 3;
    const float4* xr = reinterpret_cast<const float4*>(X + (size_t)(m0 + row) * 256);
    float sum = 0.f, sq = 0.f;
    #pragma unroll
    for (int k = 0; k < 16; ++k){
      float4 v = xr[j + 4 * k];
      sum += v.x + v.y + v.z + v.w;
      sq  += v.x*v.x + v.y*v.y + v.z*v.z + v.w*v.w;
    }
    sum += __shfl_xor(sum, 1); sq += __shfl_xor(sq, 1);
    sum += __shfl_xor(sum, 2); sq += __shfl_xor(sq, 2);
    if (j == 0){
      float mu = sum * (1.f / 256.f);
      s_mu[row] = mu;
      s_rs[row] = rsqrtf(sq * (1.f / 256.f) - mu * mu + 1e-5f);
    }
  }
  __syncthreads();

  f32x4 acc[2][8];
  #pragma unroll
  for (int mt = 0; mt < 2; ++mt)
    #pragma unroll
    for (int j = 0; j < 8; ++j) acc[mt][j] = (f32x4){0.f,0.f,0.f,0.f};

  for (int kt = 0; kt < 4; ++kt){
    __syncthreads();
    {
      const int row = tid >> 2, c0 = (tid & 3) * 16;
      const float mu = s_mu[row], rs = s_rs[row];
      const float* xp = X + (size_t)(m0 + row) * 256 + kt * 64 + c0;
      u16 v16[16];
      #pragma unroll
      for (int k = 0; k < 4; ++k){
        float4 v = *reinterpret_cast<const float4*>(xp + 4 * k);
        int col = kt * 64 + c0 + 4 * k;
        v16[4*k+0] = f2bf((v.x - mu) * rs * s_lg[col+0] + s_lb[col+0]);
        v16[4*k+1] = f2bf((v.y - mu) * rs * s_lg[col+1] + s_lb[col+1]);
        v16[4*k+2] = f2bf((v.z - mu) * rs * s_lg[col+2] + s_lb[col+2]);
        v16[4*k+3] = f2bf((v.w - mu) * rs * s_lg[col+3] + s_lb[col+3]);
      }
      int b0 = c0 >> 3;
      *reinterpret_cast<uint4*>(&sA[row * 64 + ((b0    ) ^ (row & 7)) * 8]) = *reinterpret_cast<uint4*>(&v16[0]);
      *reinterpret_cast<uint4*>(&sA[row * 64 + ((b0 + 1) ^ (row & 7)) * 8]) = *reinterpret_cast<uint4*>(&v16[8]);
    }
    #pragma unroll
    for (int i = 0; i < 4; ++i){
      int c = tid + i * 512;
      int row = c >> 3, blk = c & 7;
      *reinterpret_cast<uint4*>(&sB[row * 64 + (blk ^ (row & 7)) * 8]) =
        *reinterpret_cast<const uint4*>(w1 + (size_t)row * 256 + kt * 64 + blk * 8);
    }
    __syncthreads();
    #pragma unroll
    for (int kc = 0; kc < 2; ++kc){
      const int sw = ((kc * 4 + quad) ^ (lc & 7)) * 8;
      bf16x8 a[2], b[8];
      #pragma unroll
      for (int mt = 0; mt < 2; ++mt)
        a[mt] = *reinterpret_cast<const bf16x8*>(&sA[(m0w + mt * 16 + lc) * 64 + sw]);
      #pragma unroll
      for (int j = 0; j < 8; ++j)
        b[j] = *reinterpret_cast<const bf16x8*>(&sB[(n0w + j * 16 + lc) * 64 + sw]);
      #pragma unroll
      for (int mt = 0; mt < 2; ++mt)
        #pragma unroll
        for (int j = 0; j < 8; ++j)
          acc[mt][j] = MFMA16(a[mt], b[j], acc[mt][j]);
    }
  }
  __syncthreads();

  #pragma unroll
  for (int mt = 0; mt < 2; ++mt)
    #pragma unroll
    for (int r = 0; r < 4; ++r){
      int row = m0w + mt * 16 + quad * 4 + r;
      #pragma unroll
      for (int j = 0; j < 8; ++j){
        int col = n0w + j * 16 + lc;
        u16 v = f2bf(fmaxf(acc[mt][j][r] + s_b1[col], 0.f));
        s_h1[row * 256 + (((col >> 3) ^ (row & 31)) << 3) + (col & 7)] = v;
      }
    }

  #pragma unroll
  for (int mt = 0; mt < 2; ++mt)
    #pragma unroll
    for (int j = 0; j < 8; ++j) acc[mt][j] = (f32x4){0.f,0.f,0.f,0.f};

  for (int kt = 0; kt < 4; ++kt){
    __syncthreads();
    #pragma unroll
    for (int i = 0; i < 4; ++i){
      int c = tid + i * 512;
      int row = c >> 3, blk = c & 7;
      *reinterpret_cast<uint4*>(&sAB[row * 64 + (blk ^ (row & 7)) * 8]) =
        *reinterpret_cast<const uint4*>(w2 + (size_t)row * 256 + kt * 64 + blk * 8);
    }
    __syncthreads();
    #pragma unroll
    for (int kc = 0; kc < 2; ++kc){
      const int sw = ((kc * 4 + quad) ^ (lc & 7)) * 8;
      bf16x8 a[2], b[8];
      #pragma unroll
      for (int mt = 0; mt < 2; ++mt){
        int row = m0w + mt * 16 + lc;
        int cb = kt * 8 + kc * 4 + quad;
        a[mt] = *reinterpret_cast<const bf16x8*>(
            &s_h1[row * 256 + ((cb ^ (row & 31)) << 3)]);
      }
      #pragma unroll
      for (int j = 0; j < 8; ++j)
        b[j] = *reinterpret_cast<const bf16x8*>(&sAB[(n0w + j * 16 + lc) * 64 + sw]);
      #pragma unroll
      for (int mt = 0; mt < 2; ++mt)
        #pragma unroll
        for (int j = 0; j < 8; ++j)
          acc[mt][j] = MFMA16(a[mt], b[j], acc[mt][j]);
    }
  }

  #pragma unroll
  for (int mt = 0; mt < 2; ++mt)
    #pragma unroll
    for (int r = 0; r < 4; ++r){
      int rowl = m0w + mt * 16 + quad * 4 + r;
      const float mu = s_mu[rowl], rs = s_rs[rowl];
      size_t base = (size_t)(m0 + rowl) * 256;
      #pragma unroll
      for (int j = 0; j < 8; ++j){
        int col = n0w + j * 16 + lc;
        float xn = (X[base + col] - mu) * rs * s_lg[col] + s_lb[col];
        float v = acc[mt][j][r] + s_b2[col] + xn;
        outf[base + col] = v;
        if (obdual) obdual[base + col] = f2bf(v);
      }
    }
}

// ---------------- temporal attention (per-sample, 4 heads, MFMA) ----------------

__global__ __launch_bounds__(256) void kAttnT(
    const u16* __restrict__ Qt, const u16* __restrict__ Kt,
    const u16* __restrict__ VtT, const float* __restrict__ XN1f,
    float* __restrict__ X2)
{
  __shared__ alignas(16) u16 sQ[4][32 * 72];
  __shared__ alignas(16) u16 sK[4][32 * 72];
  __shared__ alignas(16) u16 sV[4][64 * 40];
  __shared__ alignas(16) u16 sP[4][32 * 40];

  const int tid = threadIdx.x;
  const int wv = tid >> 6, lane = tid & 63;
  const int quad = lane >> 4, lc = lane & 15;
  const int n = blockIdx.x;
  const int h = wv;
  const f32x4 zero4 = {0.f, 0.f, 0.f, 0.f};

  #pragma unroll
  for (int i = 0; i < 4; ++i){
    int c = lane + 64 * i;
    int row = c >> 3, blk = c & 7;
    *reinterpret_cast<uint4*>(&sQ[wv][row * 72 + blk * 8]) =
      *reinterpret_cast<const uint4*>(&Qt[((size_t)n * 32 + row) * 256 + h * 64 + blk * 8]);
    *reinterpret_cast<uint4*>(&sK[wv][row * 72 + blk * 8]) =
      *reinterpret_cast<const uint4*>(&Kt[((size_t)n * 32 + row) * 256 + h * 64 + blk * 8]);
    int rv = c >> 2, bv = c & 3;
    *reinterpret_cast<uint4*>(&sV[wv][rv * 40 + bv * 8]) =
      *reinterpret_cast<const uint4*>(&VtT[(((size_t)n * 4 + h) * 64 + rv) * 32 + bv * 8]);
  }
  __syncthreads();

  f32x4 s[2][2];
  #pragma unroll
  for (int mt = 0; mt < 2; ++mt)
    #pragma unroll
    for (int ct = 0; ct < 2; ++ct) s[mt][ct] = zero4;
  #pragma unroll
  for (int kc = 0; kc < 2; ++kc){
    bf16x8 aq[2], bk[2];
    #pragma unroll
    for (int mt = 0; mt < 2; ++mt)
      aq[mt] = *reinterpret_cast<const bf16x8*>(&sQ[wv][(mt * 16 + lc) * 72 + kc * 32 + quad * 8]);
    #pragma unroll
    for (int ct = 0; ct < 2; ++ct)
      bk[ct] = *reinterpret_cast<const bf16x8*>(&sK[wv][(ct * 16 + lc) * 72 + kc * 32 + quad * 8]);
    #pragma unroll
    for (int mt = 0; mt < 2; ++mt)
      #pragma unroll
      for (int ct = 0; ct < 2; ++ct)
        s[mt][ct] = MFMA16(aq[mt], bk[ct], s[mt][ct]);
  }

  #pragma unroll
  for (int mt = 0; mt < 2; ++mt){
    #pragma unroll
    for (int r = 0; r < 4; ++r){
      float v0 = s[mt][0][r], v1 = s[mt][1][r];
      float mx = fmaxf(v0, v1);
      #pragma unroll
      for (int msk = 1; msk < 16; msk <<= 1) mx = fmaxf(mx, __shfl_xor(mx, msk));
      float p0 = __expf(v0 - mx), p1 = __expf(v1 - mx);
      float sm = p0 + p1;
      #pragma unroll
      for (int msk = 1; msk < 16; msk <<= 1) sm += __shfl_xor(sm, msk);
      float inv = 1.f / sm;
      sP[wv][(mt * 16 + quad * 4 + r) * 40 + lc]      = f2bf(p0 * inv);
      sP[wv][(mt * 16 + quad * 4 + r) * 40 + lc + 16] = f2bf(p1 * inv);
    }
  }
  __syncthreads();

  #pragma unroll
  for (int mt = 0; mt < 2; ++mt){
    bf16x8 ap = *reinterpret_cast<const bf16x8*>(&sP[wv][(mt * 16 + lc) * 40 + quad * 8]);
    #pragma unroll
    for (int ct = 0; ct < 4; ++ct){
      bf16x8 bv = *reinterpret_cast<const bf16x8*>(&sV[wv][(ct * 16 + lc) * 40 + quad * 8]);
      f32x4 o = MFMA16(ap, bv, zero4);
      #pragma unroll
      for (int r = 0; r < 4; ++r){
        int t = mt * 16 + quad * 4 + r;
        size_t idx = ((size_t)n * 32 + t) * 256 + h * 64 + ct * 16 + lc;
        X2[idx] = XN1f[idx] + o[r];
      }
    }
  }
}

// ---------------- spatial flash attention (bf16 MFMA, fixed-max, key-split) ----
// grid (64, 8), 512 threads. DMA staging into unpadded XOR-swizzled layouts.

__global__ __launch_bounds__(512) void kB2_flash_mfma(
    const u16* __restrict__ Qh, const u16* __restrict__ Kh,
    const u16* __restrict__ VT, const float* __restrict__ XNs,
    float* __restrict__ XT)
{
  __shared__ alignas(16) u16 smem[26624];   // 52 KB
  u16* s_k  = smem;            // 64 x 128 (XOR-swizzled blocks of 8)
  u16* s_vt = smem + 8192;     // 128 x 64 (XOR-swizzled)
  u16* s_p  = smem + 16384;    // 8 waves * 32*40

  const int tid = threadIdx.x;
  const int wv = tid >> 6, lane = tid & 63;
  const int wq = wv & 3, wk = wv >> 2;
  const int quad = lane >> 4, lc = lane & 15;
  const int t = blockIdx.x >> 1, h = blockIdx.x & 1;
  const int n0 = blockIdx.y * 128;
  const float c_exp2 = 0.12752887f;  // log2(e)/sqrt(128)
  const int qb = n0 + wq * 32;

  bf16x8 qf[2][4];
  #pragma unroll
  for (int mt = 0; mt < 2; ++mt){
    const u16* qp = Qh + ((size_t)(t * NB + qb + mt * 16 + lc)) * DM + h * 128 + quad * 8;
    #pragma unroll
    for (int kc = 0; kc < 4; ++kc)
      qf[mt][kc] = *reinterpret_cast<const bf16x8*>(qp + kc * 32);
  }

  f32x4 o[2][8];
  #pragma unroll
  for (int mt = 0; mt < 2; ++mt)
    #pragma unroll
    for (int f = 0; f < 8; ++f) o[mt][f] = (f32x4){0.f, 0.f, 0.f, 0.f};
  float l_acc[2][4] = {{0.f,0.f,0.f,0.f},{0.f,0.f,0.f,0.f}};

  const u16* kbase  = Kh + (size_t)t * NB * DM + h * 128;
  const u16* vtbase = VT + (size_t)(t * 2 + h) * 128 * NB;
  u16* pw = s_p + wv * 1280;

  for (int j0 = 0; j0 < NB; j0 += 64){
    __syncthreads();
    // K tile: wave wv stages rows wv*8..+7 (2 DMAs x 1KB)
    #pragma unroll
    for (int i = 0; i < 2; ++i){
      int row = wv * 8 + i * 4 + (lane >> 4);
      int blk = lane & 15;
      gl2lds16(kbase + (size_t)(j0 + row) * DM + ((blk ^ (row & 15)) * 8),
               s_k + wv * 1024 + i * 512, lane);
      int rv = wv * 16 + i * 8 + (lane >> 3);
      int pv = lane & 7;
      gl2lds16(vtbase + (size_t)rv * NB + j0 + ((pv ^ (rv & 7)) * 8),
               s_vt + wv * 1024 + i * 512, lane);
    }
    __syncthreads();

    // S over this wave's 32-key half
    f32x4 s[2][2];
    #pragma unroll
    for (int mt = 0; mt < 2; ++mt)
      #pragma unroll
      for (int nt = 0; nt < 2; ++nt) s[mt][nt] = (f32x4){0.f,0.f,0.f,0.f};
    #pragma unroll
    for (int kc = 0; kc < 4; ++kc){
      #pragma unroll
      for (int nt = 0; nt < 2; ++nt){
        int krow = lc + 16 * nt + 32 * wk;
        bf16x8 bk = *reinterpret_cast<const bf16x8*>(
            &s_k[krow * 128 + (((kc * 4 + quad) ^ lc) * 8)]);
        #pragma unroll
        for (int mt = 0; mt < 2; ++mt)
          s[mt][nt] = MFMA16(qf[mt][kc], bk, s[mt][nt]);
      }
    }

    // P = exp(S/temp), per-lane partial l
    #pragma unroll
    for (int mt = 0; mt < 2; ++mt)
      #pragma unroll
      for (int nt = 0; nt < 2; ++nt)
        #pragma unroll
        for (int r = 0; r < 4; ++r){
          float p = exp2f(s[mt][nt][r] * c_exp2);
          l_acc[mt][r] += p;
          pw[(mt * 16 + quad * 4 + r) * 40 + lc + 16 * nt] = f2bf_t(p);
        }

    // O += P @ V over this wave's 32 keys
    bf16x8 ap[2];
    #pragma unroll
    for (int mt = 0; mt < 2; ++mt)
      ap[mt] = *reinterpret_cast<const bf16x8*>(&pw[(mt * 16 + lc) * 40 + quad * 8]);
    #pragma unroll
    for (int f = 0; f < 8; ++f){
      int vrow = lc + 16 * f;
      bf16x8 bv = *reinterpret_cast<const bf16x8*>(
          &s_vt[vrow * 64 + (((4 * wk + quad) ^ (lc & 7)) * 8)]);
      #pragma unroll
      for (int mt = 0; mt < 2; ++mt)
        o[mt][f] = MFMA16(ap[mt], bv, o[mt][f]);
    }
  }

  // ---- combine wave pairs (wk=0 keeps, wk=1 contributes) ----
  float* fo = (float*)smem;          // 32 KB (overlays s_k+s_vt)
  float* fl = (float*)smem + 8192;   // 8 KB (overlays s_p head)

  __syncthreads();
  if (wk == 1){
    int base = (wq * 64 + lane) * 32;
    #pragma unroll
    for (int f = 0; f < 8; ++f)
      #pragma unroll
      for (int r = 0; r < 4; ++r) fo[base + f * 4 + r] = o[0][f][r];
    int lb = (wq * 64 + lane) * 8;
    #pragma unroll
    for (int mt = 0; mt < 2; ++mt)
      #pragma unroll
      for (int r = 0; r < 4; ++r) fl[lb + mt * 4 + r] = l_acc[mt][r];
  }
  __syncthreads();
  if (wk == 0){
    int base = (wq * 64 + lane) * 32;
    #pragma unroll
    for (int f = 0; f < 8; ++f)
      #pragma unroll
      for (int r = 0; r < 4; ++r) o[0][f][r] += fo[base + f * 4 + r];
    int lb = (wq * 64 + lane) * 8;
    #pragma unroll
    for (int mt = 0; mt < 2; ++mt)
      #pragma unroll
      for (int r = 0; r < 4; ++r){
        l_acc[mt][r] += fl[lb + mt * 4 + r];
        #pragma unroll
        for (int msk = 1; msk < 16; msk <<= 1)
          l_acc[mt][r] += __shfl_xor(l_acc[mt][r], msk);
      }
    #pragma unroll
    for (int r = 0; r < 4; ++r){
      float linv = 1.f / l_acc[0][r];
      int row = qb + quad * 4 + r;
      size_t xnb = ((size_t)row * TSEQ + t) * DM + h * 128 + lc;
      size_t xtb = ((size_t)t * NB + row) * DM + h * 128 + lc;
      #pragma unroll
      for (int f = 0; f < 8; ++f)
        XT[xtb + f * 16] = XNs[xnb + f * 16] + o[0][f][r] * linv;
    }
  }
  __syncthreads();
  if (wk == 1){
    int base = (wq * 64 + lane) * 32;
    #pragma unroll
    for (int f = 0; f < 8; ++f)
      #pragma unroll
      for (int r = 0; r < 4; ++r) fo[base + f * 4 + r] = o[1][f][r];
  }
  __syncthreads();
  if (wk == 0){
    int base = (wq * 64 + lane) * 32;
    #pragma unroll
    for (int f = 0; f < 8; ++f)
      #pragma unroll
      for (int r = 0; r < 4; ++r) o[1][f][r] += fo[base + f * 4 + r];
    #pragma unroll
    for (int r = 0; r < 4; ++r){
      float linv = 1.f / l_acc[1][r];
      int row = qb + 16 + quad * 4 + r;
      size_t xnb = ((size_t)row * TSEQ + t) * DM + h * 128 + lc;
      size_t xtb = ((size_t)t * NB + row) * DM + h * 128 + lc;
      #pragma unroll
      for (int f = 0; f < 8; ++f)
        XT[xtb + f * 16] = XNs[xnb + f * 16] + o[1][f][r] * linv;
    }
  }
}

// ---------------- pooling + output head ----------------

__global__ __launch_bounds__(256) void kC_pool(
    const float* __restrict__ Ht, const float* __restrict__ ZS,
    const float* __restrict__ out_w, const float* __restrict__ out_b,
    float* __restrict__ out)
{
  __shared__ float s_z[32 * DM];
  __shared__ float s_h[32 * 260];
  __shared__ float s_sc[32];
  __shared__ float s_red[4];
  const int tid = threadIdx.x;
  const int n = blockIdx.x;

  for (int e = tid; e < 32 * DM; e += 256){
    int i = e >> 8, dd = e & 255;
    s_h[i * 260 + dd] = Ht[((size_t)i * NB + n) * DM + dd];
    s_z[e]            = ZS[((size_t)i * NB + n) * DM + dd];
  }
  __syncthreads();

  {
    const int s = tid >> 3, j = tid & 7;
    float acc = 0.f;
    #pragma unroll
    for (int k = 0; k < DM; k += 8) acc += s_h[s * 260 + k + j] * s_h[31 * 260 + k + j];
    #pragma unroll
    for (int o = 1; o < 8; o <<= 1) acc += __shfl_xor(acc, o);
    if (j == 0) s_sc[s] = acc;
  }
  __syncthreads();

  float mx = -1e30f;
  #pragma unroll
  for (int s = 0; s < 32; ++s) mx = fmaxf(mx, s_sc[s]);
  float sm = 0.f;
  #pragma unroll
  for (int s = 0; s < 32; ++s) sm += __expf(s_sc[s] - mx);
  const float inv = 1.f / sm;

  const int d = tid;
  float pooled = 0.f;
  #pragma unroll
  for (int s = 0; s < 32; ++s) pooled += __expf(s_sc[s] - mx) * inv * s_z[s * DM + d];

  float val = pooled * out_w[d];
  #pragma unroll
  for (int o = 1; o < 64; o <<= 1) val += __shfl_xor(val, o);
  if ((tid & 63) == 0) s_red[tid >> 6] = val;
  __syncthreads();
  if (tid == 0) out[n] = s_red[0] + s_red[1] + s_red[2] + s_red[3] + out_b[0];
}

// ---------------- launch ----------------

extern "C" void kernel_launch(void* const* d_in, const int* in_sizes, int n_in,
                              void* d_out, int out_size, void* d_ws, size_t ws_size,
                              hipStream_t stream)
{
  const float* x      = (const float*)d_in[0];
  const float* gate_w = (const float*)d_in[1];
  const float* gate_b = (const float*)d_in[2];
  const float* proj_w = (const float*)d_in[3];
  const float* proj_b = (const float*)d_in[4];
  const float* tq   = (const float*)d_in[5];
  const float* tk   = (const float*)d_in[6];
  const float* tv   = (const float*)d_in[7];
  const float* tn1g = (const float*)d_in[8];
  const float* tn1b = (const float*)d_in[9];
  const float* tn2g = (const float*)d_in[10];
  const float* tn2b = (const float*)d_in[11];
  const float* tf1w = (const float*)d_in[12];
  const float* tf1b = (const float*)d_in[13];
  const float* tf2w = (const float*)d_in[14];
  const float* tf2b = (const float*)d_in[15];
  const float* sq   = (const float*)d_in[16];
  const float* sk   = (const float*)d_in[17];
  const float* sv   = (const float*)d_in[18];
  const float* sn1g = (const float*)d_in[19];
  const float* sn1b = (const float*)d_in[20];
  const float* sn2g = (const float*)d_in[21];
  const float* sn2b = (const float*)d_in[22];
  const float* sf1w = (const float*)d_in[23];
  const float* sf1b = (const float*)d_in[24];
  const float* sf2w = (const float*)d_in[25];
  const float* sf2b = (const float*)d_in[26];
  const float* temp_w = (const float*)d_in[27];
  const float* out_w  = (const float*)d_in[28];
  const float* out_b  = (const float*)d_in[29];

  float* W = (float*)d_ws;
  const size_t F = (size_t)NB * TSEQ * DM;  // 8,388,608

  float* Z  = W;                  // Z / X2 / Z1 / XT / ZS  (fp32)
  float* XF = W + F;              // XN1f / XS1f / Ht
  u16* U0 = (u16*)(W + 2 * F);        // XN1b / VTs / ZSb
  u16* U1 = (u16*)(W + 2 * F) + F;    // Qt / Ks
  u16* U2 = (u16*)(W + 3 * F);        // Kt / XS1b
  u16* U3 = (u16*)(W + 3 * F) + F;    // VtT / Qs
  u16* SRC = (u16*)(W + 4 * F);       // 32768*192 bf16
  u16* WB  = (u16*)(W + 4 * F + 3145728 + 4096);

  kConvAll<<<(WB_TOT + 255) / 256, 256, 0, stream>>>(
      tq, tk, tv, sq, sk, sv, tf1w, tf2w, sf1w, sf2w, temp_w, proj_w, WB);
  kGateSrc<<<NB, 256, 0, stream>>>(x, gate_w, gate_b, SRC);
  gemm_bf16<<<dim3(256, 1), 512, 0, stream>>>(SRC, WB + 720896, 192, MODE_PROJ,
      proj_b, Z, nullptr, nullptr, nullptr);
  kLN<<<NB, 256, 0, stream>>>(Z, tn1g, tn1b, U0, XF);
  gemm_bf16<<<dim3(256, 3), 512, 0, stream>>>(U0, WB, 256, MODE_QKVT,
      nullptr, nullptr, U1, U2, U3);
  kAttnT<<<NB, 256, 0, stream>>>(U1, U2, U3, XF, Z);
  kFFN<<<256, 512, 0, stream>>>(Z, tn2g, tn2b, WB + 393216, tf1b,
      WB + 458752, tf2b, Z, nullptr);
  kLN<<<NB, 256, 0, stream>>>(Z, sn1g, sn1b, U2, XF);
  gemm_bf16<<<dim3(256, 3), 512, 0, stream>>>(U2, WB + 196608, 256, MODE_QKVS,
      nullptr, nullptr, U3, U1, U0);
  kB2_flash_mfma<<<dim3(64, 8), 512, 0, stream>>>(U3, U1, U0, XF, Z);
  kFFN<<<256, 512, 0, stream>>>(Z, sn2g, sn2b, WB + 524288, sf1b,
      WB + 589824, sf2b, Z, U0);
  gemm_bf16<<<dim3(256, 1), 512, 0, stream>>>(U0, WB + 655360, 256, MODE_TEMP,
      nullptr, XF, nullptr, nullptr, nullptr);
  kC_pool<<<NB, 256, 0, stream>>>(XF, Z, out_w, out_b, (float*)d_out);
}

// Round 12
// 478.149 us; speedup vs baseline: 1.1543x; 1.1543x over previous
//
#include <hip/hip_runtime.h>
#include <math.h>

#define NB   1024
#define TSEQ 32
#define DM   256
#define DF   158
#define GDIM 63
#define XROW 221

typedef unsigned short u16;
typedef __attribute__((ext_vector_type(8))) __bf16 bf16x8;
typedef __attribute__((ext_vector_type(4))) float f32x4;
#define MFMA16(a,b,c) __builtin_amdgcn_mfma_f32_16x16x32_bf16(a,b,c,0,0,0)

#define MODE_PROJ 0
#define MODE_QKVT 1
#define MODE_QKVS 2
#define MODE_TEMP 3

__device__ __forceinline__ u16 f2bf(float f){
  union { float f; unsigned int u; } c; c.f = f;
  unsigned int u = c.u;
  u += 0x7fffu + ((u >> 16) & 1u);   // round-to-nearest-even
  return (u16)(u >> 16);
}

// truncating bf16 (for P in attention: bias cancels between O and l)
__device__ __forceinline__ u16 f2bf_t(float f){
  union { float f; unsigned int u; } c; c.f = f;
  return (u16)(c.u >> 16);
}

// async 16B global->LDS DMA: LDS dest = wave-uniform base + lane*16.
__device__ __forceinline__ void gl2lds16(const u16* g, u16* lds_wave_base, int lane){
#if __has_builtin(__builtin_amdgcn_global_load_lds)
  __builtin_amdgcn_global_load_lds(
      (const __attribute__((address_space(1))) unsigned int*)g,
      (__attribute__((address_space(3))) unsigned int*)lds_wave_base,
      16, 0, 0);
#else
  *reinterpret_cast<uint4*>(lds_wave_base + lane * 8) =
      *reinterpret_cast<const uint4*>(g);
#endif
}

// LayerNorm over last dim (256) for a 32-row tile in LDS. 8 threads/row.
__device__ __forceinline__ void ln_rows32(float* buf, int stride,
                                          const float* __restrict__ g,
                                          const float* __restrict__ b,
                                          int tid)
{
  const int s = tid >> 3, j = tid & 7;
  float* row = buf + s * stride;
  float sum = 0.f, sq = 0.f;
  #pragma unroll
  for (int k = 0; k < DM; k += 8){
    float v = row[k + j];
    sum += v; sq += v * v;
  }
  #pragma unroll
  for (int o = 1; o < 8; o <<= 1){
    sum += __shfl_xor(sum, o);
    sq  += __shfl_xor(sq, o);
  }
  const float mu  = sum * (1.f / DM);
  const float var = sq * (1.f / DM) - mu * mu;
  const float rs  = rsqrtf(var + 1e-5f);
  #pragma unroll
  for (int k = 0; k < DM; k += 8){
    float v = row[k + j];
    row[k + j] = (v - mu) * rs * g[k + j] + b[k + j];
  }
}

// ---------------- weight conversion (fp32 -> bf16, packed) ----------------
#define WB_TOT 770048

__global__ __launch_bounds__(256) void kConvAll(
    const float* __restrict__ tq, const float* __restrict__ tk, const float* __restrict__ tv,
    const float* __restrict__ sq, const float* __restrict__ sk, const float* __restrict__ sv,
    const float* __restrict__ tf1, const float* __restrict__ tf2,
    const float* __restrict__ sf1, const float* __restrict__ sf2,
    const float* __restrict__ tw, const float* __restrict__ pw,
    u16* __restrict__ WB)
{
  int i = blockIdx.x * 256 + threadIdx.x;
  if (i >= WB_TOT) return;
  if (i < 720896){
    int j = i >> 16, o = i & 65535;
    const float* s;
    switch (j){
      case 0: s = tq; break;  case 1: s = tk; break;  case 2: s = tv; break;
      case 3: s = sq; break;  case 4: s = sk; break;  case 5: s = sv; break;
      case 6: s = tf1; break; case 7: s = tf2; break;
      case 8: s = sf1; break; case 9: s = sf2; break;
      default: s = tw; break;
    }
    WB[i] = f2bf(s[o]);
  } else {
    int k = i - 720896;
    int row = k / 192, col = k - row * 192;
    WB[i] = (col < DF) ? f2bf(pw[row * DF + col]) : (u16)0;
  }
}

// ---------------- gate + gated src (bf16, K padded to 192) ----------------

__global__ __launch_bounds__(256) void kGateSrc(
    const float* __restrict__ x,
    const float* __restrict__ gate_w, const float* __restrict__ gate_b,
    u16* __restrict__ SRC)
{
  __shared__ float s_gate[DF];
  __shared__ float s_gi[GDIM];
  const int tid = threadIdx.x;
  const int n = blockIdx.x;

  if (tid < GDIM) s_gi[tid] = x[(n * TSEQ + (TSEQ - 1)) * XROW + DF + tid];
  __syncthreads();
  float logit = 0.f;
  if (tid < DF){
    logit = gate_b[tid];
    const float* __restrict__ wr = gate_w + tid * GDIM;
    for (int g = 0; g < GDIM; ++g) logit += s_gi[g] * wr[g];
    logit *= 0.2f;
    s_gate[tid] = logit;
  }
  __syncthreads();
  {
    float mx = -1e30f;
    for (int f = 0; f < DF; ++f) mx = fmaxf(mx, s_gate[f]);
    float sm = 0.f;
    for (int f = 0; f < DF; ++f) sm += __expf(s_gate[f] - mx);
    __syncthreads();
    if (tid < DF) s_gate[tid] = (float)DF * __expf(logit - mx) / sm;
  }
  __syncthreads();

  for (int e = tid; e < TSEQ * 192; e += 256){
    int t = e / 192, f = e - t * 192;
    float v = 0.f;
    if (f < DF) v = x[(n * TSEQ + t) * XROW + f] * s_gate[f];
    SRC[(size_t)(n * TSEQ + t) * 192 + f] = f2bf(v);
  }
}

// ---------------- generic bf16 MFMA GEMM: C = A[M x K] @ B[N x K]^T ----------------
// MODE_QKVS uses a t-major row-block mapping (full-line V^T scatter writes).

__global__ __launch_bounds__(256) void gemm_bf16(
    const u16* __restrict__ A, const u16* __restrict__ B,
    const int K, const int mode,
    const float* __restrict__ bias,
    float* __restrict__ outf,
    u16* __restrict__ ob0, u16* __restrict__ ob1, u16* __restrict__ ob2)
{
  __shared__ alignas(16) u16 sA[128 * 64];
  __shared__ alignas(16) u16 sB[128 * 64];
  const int tid = threadIdx.x;
  const int wv = tid >> 6, lane = tid & 63;
  const int wr = wv >> 1, wc = wv & 1;
  const int quad = lane >> 4, lc = lane & 15;
  const int n0 = blockIdx.y * 128;
  const bool tmaj = (mode == MODE_QKVS);
  const int tt = tmaj ? (blockIdx.x & 31) : 0;
  const int nb = tmaj ? (blockIdx.x >> 5) : 0;
  const int m0 = tmaj ? 0 : blockIdx.x * 128;

  f32x4 acc[4][4];
  #pragma unroll
  for (int i = 0; i < 4; ++i)
    #pragma unroll
    for (int j = 0; j < 4; ++j) acc[i][j] = (f32x4){0.f,0.f,0.f,0.f};

  for (int kt = 0; kt < K; kt += 64){
    __syncthreads();
    #pragma unroll
    for (int j = 0; j < 4; ++j){
      int c = wv * 64 + lane + j * 256;
      int row = c >> 3, blk = c & 7;
      int arow = tmaj ? ((nb * 128 + row) * 32 + tt) : (m0 + row);
      gl2lds16(A + (size_t)arow * K + kt + ((blk ^ (row & 7)) * 8),
               &sA[(wv * 64 + j * 256) * 8], lane);
      gl2lds16(B + (size_t)(n0 + row) * K + kt + ((blk ^ (row & 7)) * 8),
               &sB[(wv * 64 + j * 256) * 8], lane);
    }
    __syncthreads();
    #pragma unroll
    for (int kc = 0; kc < 2; ++kc){
      const int sw = ((kc * 4 + quad) ^ (lc & 7)) * 8;
      bf16x8 a[4], b[4];
      #pragma unroll
      for (int i = 0; i < 4; ++i){
        a[i] = *reinterpret_cast<const bf16x8*>(&sA[(wr * 64 + i * 16 + lc) * 64 + sw]);
        b[i] = *reinterpret_cast<const bf16x8*>(&sB[(wc * 64 + i * 16 + lc) * 64 + sw]);
      }
      #pragma unroll
      for (int i = 0; i < 4; ++i)
        #pragma unroll
        for (int j = 0; j < 4; ++j)
          acc[i][j] = MFMA16(a[i], b[j], acc[i][j]);
    }
  }

  // -------- epilogue --------
  const int rb = wr * 64 + quad * 4;
  const int cb = wc * 64 + lc;

  if (mode == MODE_PROJ){
    #pragma unroll
    for (int i = 0; i < 4; ++i)
      #pragma unroll
      for (int r = 0; r < 4; ++r){
        int row = m0 + rb + i * 16 + r;
        float ft = (float)(row & 31);
        #pragma unroll
        for (int j = 0; j < 4; ++j){
          int col = n0 + cb + j * 16;
          float div = __expf((float)(col & ~1) * -0.035977892f);
          float ang = ft * div;
          float pe = (col & 1) ? __cosf(ang) : __sinf(ang);
          outf[(size_t)row * 256 + col] = acc[i][j][r] + bias[col] + pe;
        }
      }
  } else if (mode == MODE_QKVT){
    #pragma unroll
    for (int i = 0; i < 4; ++i)
      #pragma unroll
      for (int r = 0; r < 4; ++r){
        int row = m0 + rb + i * 16 + r;
        #pragma unroll
        for (int j = 0; j < 4; ++j){
          int col = n0 + cb + j * 16;
          int sel = col >> 8, c = col & 255;
          u16 v = f2bf(acc[i][j][r]);
          if (sel == 0)      ob0[(size_t)row * 256 + c] = v;
          else if (sel == 1) ob1[(size_t)row * 256 + c] = v;
          else {
            int h = c >> 6, dd = c & 63;
            ob2[(((size_t)(row >> 5) * 4 + h) * 64 + dd) * 32 + (row & 31)] = v;
          }
        }
      }
  } else if (mode == MODE_QKVS){
    #pragma unroll
    for (int i = 0; i < 4; ++i)
      #pragma unroll
      for (int r = 0; r < 4; ++r){
        int rl = rb + i * 16 + r;
        int n = nb * 128 + rl;
        #pragma unroll
        for (int j = 0; j < 4; ++j){
          int col = n0 + cb + j * 16;
          int sel = col >> 8, c = col & 255;
          u16 v = f2bf(acc[i][j][r]);
          if (sel == 0)      ob0[((size_t)tt * NB + n) * 256 + c] = v;
          else if (sel == 1) ob1[((size_t)tt * NB + n) * 256 + c] = v;
          else {
            int h = c >> 7, dd = c & 127;
            ob2[(((size_t)tt * 2 + h) * 128 + dd) * NB + n] = v;
          }
        }
      }
  } else { // MODE_TEMP
    #pragma unroll
    for (int i = 0; i < 4; ++i)
      #pragma unroll
      for (int r = 0; r < 4; ++r){
        int row = m0 + rb + i * 16 + r;
        #pragma unroll
        for (int j = 0; j < 4; ++j){
          int col = n0 + cb + j * 16;
          outf[(size_t)row * 256 + col] = acc[i][j][r];
        }
      }
  }
}

// ---------------- generic LayerNorm: fp32 in -> bf16 + fp32 out ----------------

__global__ __launch_bounds__(256) void kLN(
    const float* __restrict__ X, const float* __restrict__ g,
    const float* __restrict__ b,
    u16* __restrict__ Xb, float* __restrict__ Xf)
{
  __shared__ float s_z[32 * DM];
  const int tid = threadIdx.x;
  const size_t base = (size_t)blockIdx.x * (32 * DM);
  for (int e = tid; e < 32 * DM; e += 256) s_z[e] = X[base + e];
  __syncthreads();
  ln_rows32(s_z, DM, g, b, tid);
  __syncthreads();
  for (int e = tid; e < 32 * DM; e += 256){
    float v = s_z[e];
    Xb[base + e] = f2bf(v);
    Xf[base + e] = v;
  }
}

// ---------------- fused LN2 + FFN ----------------

__global__ __launch_bounds__(512) void kFFN(
    const float* __restrict__ X,
    const float* __restrict__ lg, const float* __restrict__ lb,
    const u16* __restrict__ w1, const float* __restrict__ b1,
    const u16* __restrict__ w2, const float* __restrict__ b2,
    float* __restrict__ outf, u16* __restrict__ obdual)
{
  __shared__ alignas(16) u16 sAB[24576];
  __shared__ alignas(16) u16 s_h1[128 * 256];
  __shared__ float s_mu[128], s_rs[128];
  __shared__ float s_lg[256], s_lb[256], s_b1[256], s_b2[256];

  const int tid = threadIdx.x;
  const int wv = tid >> 6, lane = tid & 63;
  const int quad = lane >> 4, lc = lane & 15;
  const int m0 = blockIdx.x * 128;
  const int m0w = (wv >> 1) * 32;
  const int n0w = (wv & 1) * 128;
  u16* sA = sAB;
  u16* sB = sAB + 8192;

  if (tid < 256){
    s_lg[tid] = lg[tid]; s_lb[tid] = lb[tid];
    s_b1[tid] = b1[tid]; s_b2[tid] = b2[tid];
  }

  {
    const int row = tid >> 2, j = tid & 3;
    const float4* xr = reinterpret_cast<const float4*>(X + (size_t)(m0 + row) * 256);
    float sum = 0.f, sq = 0.f;
    #pragma unroll
    for (int k = 0; k < 16; ++k){
      float4 v = xr[j + 4 * k];
      sum += v.x + v.y + v.z + v.w;
      sq  += v.x*v.x + v.y*v.y + v.z*v.z + v.w*v.w;
    }
    sum += __shfl_xor(sum, 1); sq += __shfl_xor(sq, 1);
    sum += __shfl_xor(sum, 2); sq += __shfl_xor(sq, 2);
    if (j == 0){
      float mu = sum * (1.f / 256.f);
      s_mu[row] = mu;
      s_rs[row] = rsqrtf(sq * (1.f / 256.f) - mu * mu + 1e-5f);
    }
  }
  __syncthreads();

  f32x4 acc[2][8];
  #pragma unroll
  for (int mt = 0; mt < 2; ++mt)
    #pragma unroll
    for (int j = 0; j < 8; ++j) acc[mt][j] = (f32x4){0.f,0.f,0.f,0.f};

  for (int kt = 0; kt < 4; ++kt){
    __syncthreads();
    {
      const int row = tid >> 2, c0 = (tid & 3) * 16;
      const float mu = s_mu[row], rs = s_rs[row];
      const float* xp = X + (size_t)(m0 + row) * 256 + kt * 64 + c0;
      u16 v16[16];
      #pragma unroll
      for (int k = 0; k < 4; ++k){
        float4 v = *reinterpret_cast<const float4*>(xp + 4 * k);
        int col = kt * 64 + c0 + 4 * k;
        v16[4*k+0] = f2bf((v.x - mu) * rs * s_lg[col+0] + s_lb[col+0]);
        v16[4*k+1] = f2bf((v.y - mu) * rs * s_lg[col+1] + s_lb[col+1]);
        v16[4*k+2] = f2bf((v.z - mu) * rs * s_lg[col+2] + s_lb[col+2]);
        v16[4*k+3] = f2bf((v.w - mu) * rs * s_lg[col+3] + s_lb[col+3]);
      }
      int b0 = c0 >> 3;
      *reinterpret_cast<uint4*>(&sA[row * 64 + ((b0    ) ^ (row & 7)) * 8]) = *reinterpret_cast<uint4*>(&v16[0]);
      *reinterpret_cast<uint4*>(&sA[row * 64 + ((b0 + 1) ^ (row & 7)) * 8]) = *reinterpret_cast<uint4*>(&v16[8]);
    }
    #pragma unroll
    for (int i = 0; i < 4; ++i){
      int c = tid + i * 512;
      int row = c >> 3, blk = c & 7;
      *reinterpret_cast<uint4*>(&sB[row * 64 + (blk ^ (row & 7)) * 8]) =
        *reinterpret_cast<const uint4*>(w1 + (size_t)row * 256 + kt * 64 + blk * 8);
    }
    __syncthreads();
    #pragma unroll
    for (int kc = 0; kc < 2; ++kc){
      const int sw = ((kc * 4 + quad) ^ (lc & 7)) * 8;
      bf16x8 a[2], b[8];
      #pragma unroll
      for (int mt = 0; mt < 2; ++mt)
        a[mt] = *reinterpret_cast<const bf16x8*>(&sA[(m0w + mt * 16 + lc) * 64 + sw]);
      #pragma unroll
      for (int j = 0; j < 8; ++j)
        b[j] = *reinterpret_cast<const bf16x8*>(&sB[(n0w + j * 16 + lc) * 64 + sw]);
      #pragma unroll
      for (int mt = 0; mt < 2; ++mt)
        #pragma unroll
        for (int j = 0; j < 8; ++j)
          acc[mt][j] = MFMA16(a[mt], b[j], acc[mt][j]);
    }
  }
  __syncthreads();

  #pragma unroll
  for (int mt = 0; mt < 2; ++mt)
    #pragma unroll
    for (int r = 0; r < 4; ++r){
      int row = m0w + mt * 16 + quad * 4 + r;
      #pragma unroll
      for (int j = 0; j < 8; ++j){
        int col = n0w + j * 16 + lc;
        u16 v = f2bf(fmaxf(acc[mt][j][r] + s_b1[col], 0.f));
        s_h1[row * 256 + (((col >> 3) ^ (row & 31)) << 3) + (col & 7)] = v;
      }
    }

  #pragma unroll
  for (int mt = 0; mt < 2; ++mt)
    #pragma unroll
    for (int j = 0; j < 8; ++j) acc[mt][j] = (f32x4){0.f,0.f,0.f,0.f};

  for (int kt = 0; kt < 4; ++kt){
    __syncthreads();
    #pragma unroll
    for (int i = 0; i < 4; ++i){
      int c = tid + i * 512;
      int row = c >> 3, blk = c & 7;
      *reinterpret_cast<uint4*>(&sAB[row * 64 + (blk ^ (row & 7)) * 8]) =
        *reinterpret_cast<const uint4*>(w2 + (size_t)row * 256 + kt * 64 + blk * 8);
    }
    __syncthreads();
    #pragma unroll
    for (int kc = 0; kc < 2; ++kc){
      const int sw = ((kc * 4 + quad) ^ (lc & 7)) * 8;
      bf16x8 a[2], b[8];
      #pragma unroll
      for (int mt = 0; mt < 2; ++mt){
        int row = m0w + mt * 16 + lc;
        int cb = kt * 8 + kc * 4 + quad;
        a[mt] = *reinterpret_cast<const bf16x8*>(
            &s_h1[row * 256 + ((cb ^ (row & 31)) << 3)]);
      }
      #pragma unroll
      for (int j = 0; j < 8; ++j)
        b[j] = *reinterpret_cast<const bf16x8*>(&sAB[(n0w + j * 16 + lc) * 64 + sw]);
      #pragma unroll
      for (int mt = 0; mt < 2; ++mt)
        #pragma unroll
        for (int j = 0; j < 8; ++j)
          acc[mt][j] = MFMA16(a[mt], b[j], acc[mt][j]);
    }
  }

  #pragma unroll
  for (int mt = 0; mt < 2; ++mt)
    #pragma unroll
    for (int r = 0; r < 4; ++r){
      int rowl = m0w + mt * 16 + quad * 4 + r;
      const float mu = s_mu[rowl], rs = s_rs[rowl];
      size_t base = (size_t)(m0 + rowl) * 256;
      #pragma unroll
      for (int j = 0; j < 8; ++j){
        int col = n0w + j * 16 + lc;
        float xn = (X[base + col] - mu) * rs * s_lg[col] + s_lb[col];
        float v = acc[mt][j][r] + s_b2[col] + xn;
        outf[base + col] = v;
        if (obdual) obdual[base + col] = f2bf(v);
      }
    }
}

// ---------------- temporal attention (per-sample, 4 heads, MFMA) ----------------

__global__ __launch_bounds__(256) void kAttnT(
    const u16* __restrict__ Qt, const u16* __restrict__ Kt,
    const u16* __restrict__ VtT, const float* __restrict__ XN1f,
    float* __restrict__ X2)
{
  __shared__ alignas(16) u16 sQ[4][32 * 72];
  __shared__ alignas(16) u16 sK[4][32 * 72];
  __shared__ alignas(16) u16 sV[4][64 * 40];
  __shared__ alignas(16) u16 sP[4][32 * 40];

  const int tid = threadIdx.x;
  const int wv = tid >> 6, lane = tid & 63;
  const int quad = lane >> 4, lc = lane & 15;
  const int n = blockIdx.x;
  const int h = wv;
  const f32x4 zero4 = {0.f, 0.f, 0.f, 0.f};

  #pragma unroll
  for (int i = 0; i < 4; ++i){
    int c = lane + 64 * i;
    int row = c >> 3, blk = c & 7;
    *reinterpret_cast<uint4*>(&sQ[wv][row * 72 + blk * 8]) =
      *reinterpret_cast<const uint4*>(&Qt[((size_t)n * 32 + row) * 256 + h * 64 + blk * 8]);
    *reinterpret_cast<uint4*>(&sK[wv][row * 72 + blk * 8]) =
      *reinterpret_cast<const uint4*>(&Kt[((size_t)n * 32 + row) * 256 + h * 64 + blk * 8]);
    int rv = c >> 2, bv = c & 3;
    *reinterpret_cast<uint4*>(&sV[wv][rv * 40 + bv * 8]) =
      *reinterpret_cast<const uint4*>(&VtT[(((size_t)n * 4 + h) * 64 + rv) * 32 + bv * 8]);
  }
  __syncthreads();

  f32x4 s[2][2];
  #pragma unroll
  for (int mt = 0; mt < 2; ++mt)
    #pragma unroll
    for (int ct = 0; ct < 2; ++ct) s[mt][ct] = zero4;
  #pragma unroll
  for (int kc = 0; kc < 2; ++kc){
    bf16x8 aq[2], bk[2];
    #pragma unroll
    for (int mt = 0; mt < 2; ++mt)
      aq[mt] = *reinterpret_cast<const bf16x8*>(&sQ[wv][(mt * 16 + lc) * 72 + kc * 32 + quad * 8]);
    #pragma unroll
    for (int ct = 0; ct < 2; ++ct)
      bk[ct] = *reinterpret_cast<const bf16x8*>(&sK[wv][(ct * 16 + lc) * 72 + kc * 32 + quad * 8]);
    #pragma unroll
    for (int mt = 0; mt < 2; ++mt)
      #pragma unroll
      for (int ct = 0; ct < 2; ++ct)
        s[mt][ct] = MFMA16(aq[mt], bk[ct], s[mt][ct]);
  }

  #pragma unroll
  for (int mt = 0; mt < 2; ++mt){
    #pragma unroll
    for (int r = 0; r < 4; ++r){
      float v0 = s[mt][0][r], v1 = s[mt][1][r];
      float mx = fmaxf(v0, v1);
      #pragma unroll
      for (int msk = 1; msk < 16; msk <<= 1) mx = fmaxf(mx, __shfl_xor(mx, msk));
      float p0 = __expf(v0 - mx), p1 = __expf(v1 - mx);
      float sm = p0 + p1;
      #pragma unroll
      for (int msk = 1; msk < 16; msk <<= 1) sm += __shfl_xor(sm, msk);
      float inv = 1.f / sm;
      sP[wv][(mt * 16 + quad * 4 + r) * 40 + lc]      = f2bf(p0 * inv);
      sP[wv][(mt * 16 + quad * 4 + r) * 40 + lc + 16] = f2bf(p1 * inv);
    }
  }
  __syncthreads();

  #pragma unroll
  for (int mt = 0; mt < 2; ++mt){
    bf16x8 ap = *reinterpret_cast<const bf16x8*>(&sP[wv][(mt * 16 + lc) * 40 + quad * 8]);
    #pragma unroll
    for (int ct = 0; ct < 4; ++ct){
      bf16x8 bv = *reinterpret_cast<const bf16x8*>(&sV[wv][(ct * 16 + lc) * 40 + quad * 8]);
      f32x4 o = MFMA16(ap, bv, zero4);
      #pragma unroll
      for (int r = 0; r < 4; ++r){
        int t = mt * 16 + quad * 4 + r;
        size_t idx = ((size_t)n * 32 + t) * 256 + h * 64 + ct * 16 + lc;
        X2[idx] = XN1f[idx] + o[r];
      }
    }
  }
}

// ---------------- spatial flash attention (bf16 MFMA, fixed-max, key-split waves) ----
// grid (64, 8), 512 threads = 8 waves. wq = wv&3 owns q-rows, wk = wv>>2 owns
// key-half of each staged 64-key tile. Partial O/l per wave (fixed-max softmax
// composes additively), combined once at the end via LDS.

__global__ __launch_bounds__(512) void kB2_flash_mfma(
    const u16* __restrict__ Qh, const u16* __restrict__ Kh,
    const u16* __restrict__ VT, const float* __restrict__ XNs,
    float* __restrict__ XT)
{
  __shared__ alignas(16) u16 smem[28160];   // 55 KB flat
  u16* s_k  = smem;                          // 64*136
  u16* s_vt = smem + 8704;                   // 128*72
  u16* s_p  = smem + 17920;                  // 8 waves * 32*40

  const int tid = threadIdx.x;
  const int wv = tid >> 6, lane = tid & 63;
  const int wq = wv & 3, wk = wv >> 2;
  const int quad = lane >> 4, lc = lane & 15;
  const int t = blockIdx.x >> 1, h = blockIdx.x & 1;
  const int n0 = blockIdx.y * 128;
  const float c_exp2 = 0.12752887f;  // log2(e)/sqrt(128)
  const int qb = n0 + wq * 32;

  bf16x8 qf[2][4];
  #pragma unroll
  for (int mt = 0; mt < 2; ++mt){
    const u16* qp = Qh + ((size_t)(t * NB + qb + mt * 16 + lc)) * DM + h * 128 + quad * 8;
    #pragma unroll
    for (int kc = 0; kc < 4; ++kc)
      qf[mt][kc] = *reinterpret_cast<const bf16x8*>(qp + kc * 32);
  }

  f32x4 o[2][8];
  #pragma unroll
  for (int mt = 0; mt < 2; ++mt)
    #pragma unroll
    for (int f = 0; f < 8; ++f) o[mt][f] = (f32x4){0.f, 0.f, 0.f, 0.f};
  float l_acc[2][4] = {{0.f,0.f,0.f,0.f},{0.f,0.f,0.f,0.f}};

  const u16* kbase  = Kh + (size_t)t * NB * DM + h * 128;
  const u16* vtbase = VT + (size_t)(t * 2 + h) * 128 * NB;
  u16* pw = s_p + wv * 1280;

  for (int j0 = 0; j0 < NB; j0 += 64){
    __syncthreads();
    #pragma unroll
    for (int it = 0; it < 2; ++it){
      int c = tid + it * 512;
      int row = c >> 4, part = c & 15;   // K tile: 64 x 128
      *reinterpret_cast<uint4*>(&s_k[row * 136 + part * 8]) =
        *reinterpret_cast<const uint4*>(kbase + (size_t)(j0 + row) * DM + part * 8);
      int rv = c >> 3, pv = c & 7;       // VT tile: 128 x 64
      *reinterpret_cast<uint4*>(&s_vt[rv * 72 + pv * 8]) =
        *reinterpret_cast<const uint4*>(vtbase + (size_t)rv * NB + j0 + pv * 8);
    }
    __syncthreads();

    // S over this wave's 32-key half
    f32x4 s[2][2];
    #pragma unroll
    for (int mt = 0; mt < 2; ++mt)
      #pragma unroll
      for (int nt = 0; nt < 2; ++nt) s[mt][nt] = (f32x4){0.f,0.f,0.f,0.f};
    #pragma unroll
    for (int kc = 0; kc < 4; ++kc){
      #pragma unroll
      for (int nt = 0; nt < 2; ++nt){
        bf16x8 bk = *reinterpret_cast<const bf16x8*>(
            &s_k[(lc + 16 * nt + 32 * wk) * 136 + kc * 32 + quad * 8]);
        #pragma unroll
        for (int mt = 0; mt < 2; ++mt)
          s[mt][nt] = MFMA16(qf[mt][kc], bk, s[mt][nt]);
      }
    }

    // P = exp(S/temp), per-lane partial l
    #pragma unroll
    for (int mt = 0; mt < 2; ++mt)
      #pragma unroll
      for (int nt = 0; nt < 2; ++nt)
        #pragma unroll
        for (int r = 0; r < 4; ++r){
          float p = exp2f(s[mt][nt][r] * c_exp2);
          l_acc[mt][r] += p;
          pw[(mt * 16 + quad * 4 + r) * 40 + lc + 16 * nt] = f2bf_t(p);
        }

    // O += P @ V over this wave's 32 keys
    bf16x8 ap[2];
    #pragma unroll
    for (int mt = 0; mt < 2; ++mt)
      ap[mt] = *reinterpret_cast<const bf16x8*>(&pw[(mt * 16 + lc) * 40 + quad * 8]);
    #pragma unroll
    for (int f = 0; f < 8; ++f){
      bf16x8 bv = *reinterpret_cast<const bf16x8*>(
          &s_vt[(lc + 16 * f) * 72 + 32 * wk + quad * 8]);
      #pragma unroll
      for (int mt = 0; mt < 2; ++mt)
        o[mt][f] = MFMA16(ap[mt], bv, o[mt][f]);
    }
  }

  // ---- combine wave pairs (wk=0 keeps, wk=1 contributes) ----
  float* fo = (float*)smem;          // 4 wq * 64 lanes * 32 f32 = 32 KB
  float* fl = (float*)smem + 8192;   // 4 wq * 64 lanes * 8 f32  = 8 KB

  __syncthreads();
  if (wk == 1){
    int base = (wq * 64 + lane) * 32;
    #pragma unroll
    for (int f = 0; f < 8; ++f)
      #pragma unroll
      for (int r = 0; r < 4; ++r) fo[base + f * 4 + r] = o[0][f][r];
    int lb = (wq * 64 + lane) * 8;
    #pragma unroll
    for (int mt = 0; mt < 2; ++mt)
      #pragma unroll
      for (int r = 0; r < 4; ++r) fl[lb + mt * 4 + r] = l_acc[mt][r];
  }
  __syncthreads();
  if (wk == 0){
    int base = (wq * 64 + lane) * 32;
    #pragma unroll
    for (int f = 0; f < 8; ++f)
      #pragma unroll
      for (int r = 0; r < 4; ++r) o[0][f][r] += fo[base + f * 4 + r];
    int lb = (wq * 64 + lane) * 8;
    #pragma unroll
    for (int mt = 0; mt < 2; ++mt)
      #pragma unroll
      for (int r = 0; r < 4; ++r){
        l_acc[mt][r] += fl[lb + mt * 4 + r];
        #pragma unroll
        for (int msk = 1; msk < 16; msk <<= 1)
          l_acc[mt][r] += __shfl_xor(l_acc[mt][r], msk);
      }
    // epilogue mt=0
    #pragma unroll
    for (int r = 0; r < 4; ++r){
      float linv = 1.f / l_acc[0][r];
      int row = qb + quad * 4 + r;
      size_t xnb = ((size_t)row * TSEQ + t) * DM + h * 128 + lc;
      size_t xtb = ((size_t)t * NB + row) * DM + h * 128 + lc;
      #pragma unroll
      for (int f = 0; f < 8; ++f)
        XT[xtb + f * 16] = XNs[xnb + f * 16] + o[0][f][r] * linv;
    }
  }
  __syncthreads();
  if (wk == 1){
    int base = (wq * 64 + lane) * 32;
    #pragma unroll
    for (int f = 0; f < 8; ++f)
      #pragma unroll
      for (int r = 0; r < 4; ++r) fo[base + f * 4 + r] = o[1][f][r];
  }
  __syncthreads();
  if (wk == 0){
    int base = (wq * 64 + lane) * 32;
    #pragma unroll
    for (int f = 0; f < 8; ++f)
      #pragma unroll
      for (int r = 0; r < 4; ++r) o[1][f][r] += fo[base + f * 4 + r];
    #pragma unroll
    for (int r = 0; r < 4; ++r){
      float linv = 1.f / l_acc[1][r];
      int row = qb + 16 + quad * 4 + r;
      size_t xnb = ((size_t)row * TSEQ + t) * DM + h * 128 + lc;
      size_t xtb = ((size_t)t * NB + row) * DM + h * 128 + lc;
      #pragma unroll
      for (int f = 0; f < 8; ++f)
        XT[xtb + f * 16] = XNs[xnb + f * 16] + o[1][f][r] * linv;
    }
  }
}

// ---------------- pooling + output head ----------------

__global__ __launch_bounds__(256) void kC_pool(
    const float* __restrict__ Ht, const float* __restrict__ ZS,
    const float* __restrict__ out_w, const float* __restrict__ out_b,
    float* __restrict__ out)
{
  __shared__ float s_z[32 * DM];
  __shared__ float s_h[32 * 260];
  __shared__ float s_sc[32];
  __shared__ float s_red[4];
  const int tid = threadIdx.x;
  const int n = blockIdx.x;

  for (int e = tid; e < 32 * DM; e += 256){
    int i = e >> 8, dd = e & 255;
    s_h[i * 260 + dd] = Ht[((size_t)i * NB + n) * DM + dd];
    s_z[e]            = ZS[((size_t)i * NB + n) * DM + dd];
  }
  __syncthreads();

  {
    const int s = tid >> 3, j = tid & 7;
    float acc = 0.f;
    #pragma unroll
    for (int k = 0; k < DM; k += 8) acc += s_h[s * 260 + k + j] * s_h[31 * 260 + k + j];
    #pragma unroll
    for (int o = 1; o < 8; o <<= 1) acc += __shfl_xor(acc, o);
    if (j == 0) s_sc[s] = acc;
  }
  __syncthreads();

  float mx = -1e30f;
  #pragma unroll
  for (int s = 0; s < 32; ++s) mx = fmaxf(mx, s_sc[s]);
  float sm = 0.f;
  #pragma unroll
  for (int s = 0; s < 32; ++s) sm += __expf(s_sc[s] - mx);
  const float inv = 1.f / sm;

  const int d = tid;
  float pooled = 0.f;
  #pragma unroll
  for (int s = 0; s < 32; ++s) pooled += __expf(s_sc[s] - mx) * inv * s_z[s * DM + d];

  float val = pooled * out_w[d];
  #pragma unroll
  for (int o = 1; o < 64; o <<= 1) val += __shfl_xor(val, o);
  if ((tid & 63) == 0) s_red[tid >> 6] = val;
  __syncthreads();
  if (tid == 0) out[n] = s_red[0] + s_red[1] + s_red[2] + s_red[3] + out_b[0];
}

// ---------------- launch ----------------

extern "C" void kernel_launch(void* const* d_in, const int* in_sizes, int n_in,
                              void* d_out, int out_size, void* d_ws, size_t ws_size,
                              hipStream_t stream)
{
  const float* x      = (const float*)d_in[0];
  const float* gate_w = (const float*)d_in[1];
  const float* gate_b = (const float*)d_in[2];
  const float* proj_w = (const float*)d_in[3];
  const float* proj_b = (const float*)d_in[4];
  const float* tq   = (const float*)d_in[5];
  const float* tk   = (const float*)d_in[6];
  const float* tv   = (const float*)d_in[7];
  const float* tn1g = (const float*)d_in[8];
  const float* tn1b = (const float*)d_in[9];
  const float* tn2g = (const float*)d_in[10];
  const float* tn2b = (const float*)d_in[11];
  const float* tf1w = (const float*)d_in[12];
  const float* tf1b = (const float*)d_in[13];
  const float* tf2w = (const float*)d_in[14];
  const float* tf2b = (const float*)d_in[15];
  const float* sq   = (const float*)d_in[16];
  const float* sk   = (const float*)d_in[17];
  const float* sv   = (const float*)d_in[18];
  const float* sn1g = (const float*)d_in[19];
  const float* sn1b = (const float*)d_in[20];
  const float* sn2g = (const float*)d_in[21];
  const float* sn2b = (const float*)d_in[22];
  const float* sf1w = (const float*)d_in[23];
  const float* sf1b = (const float*)d_in[24];
  const float* sf2w = (const float*)d_in[25];
  const float* sf2b = (const float*)d_in[26];
  const float* temp_w = (const float*)d_in[27];
  const float* out_w  = (const float*)d_in[28];
  const float* out_b  = (const float*)d_in[29];

  float* W = (float*)d_ws;
  const size_t F = (size_t)NB * TSEQ * DM;  // 8,388,608

  float* Z  = W;                  // Z / X2 / Z1 / XT / ZS  (fp32)
  float* XF = W + F;              // XN1f / XS1f / Ht
  u16* U0 = (u16*)(W + 2 * F);        // XN1b / VTs / ZSb
  u16* U1 = (u16*)(W + 2 * F) + F;    // Qt / Ks
  u16* U2 = (u16*)(W + 3 * F);        // Kt / XS1b
  u16* U3 = (u16*)(W + 3 * F) + F;    // VtT / Qs
  u16* SRC = (u16*)(W + 4 * F);       // 32768*192 bf16
  u16* WB  = (u16*)(W + 4 * F + 3145728 + 4096);

  kConvAll<<<(WB_TOT + 255) / 256, 256, 0, stream>>>(
      tq, tk, tv, sq, sk, sv, tf1w, tf2w, sf1w, sf2w, temp_w, proj_w, WB);
  kGateSrc<<<NB, 256, 0, stream>>>(x, gate_w, gate_b, SRC);
  gemm_bf16<<<dim3(256, 2), 256, 0, stream>>>(SRC, WB + 720896, 192, MODE_PROJ,
      proj_b, Z, nullptr, nullptr, nullptr);
  kLN<<<NB, 256, 0, stream>>>(Z, tn1g, tn1b, U0, XF);
  gemm_bf16<<<dim3(256, 6), 256, 0, stream>>>(U0, WB, 256, MODE_QKVT,
      nullptr, nullptr, U1, U2, U3);
  kAttnT<<<NB, 256, 0, stream>>>(U1, U2, U3, XF, Z);
  kFFN<<<256, 512, 0, stream>>>(Z, tn2g, tn2b, WB + 393216, tf1b,
      WB + 458752, tf2b, Z, nullptr);
  kLN<<<NB, 256, 0, stream>>>(Z, sn1g, sn1b, U2, XF);
  gemm_bf16<<<dim3(256, 6), 256, 0, stream>>>(U2, WB + 196608, 256, MODE_QKVS,
      nullptr, nullptr, U3, U1, U0);
  kB2_flash_mfma<<<dim3(64, 8), 512, 0, stream>>>(U3, U1, U0, XF, Z);
  kFFN<<<256, 512, 0, stream>>>(Z, sn2g, sn2b, WB + 524288, sf1b,
      WB + 589824, sf2b, Z, U0);
  gemm_bf16<<<dim3(256, 2), 256, 0, stream>>>(U0, WB + 655360, 256, MODE_TEMP,
      nullptr, XF, nullptr, nullptr, nullptr);
  kC_pool<<<NB, 256, 0, stream>>>(XF, Z, out_w, out_b, (float*)d_out);
}

// Round 13
// 450.331 us; speedup vs baseline: 1.2256x; 1.0618x over previous
//
#include <hip/hip_runtime.h>
#include <math.h>

#define NB   1024
#define TSEQ 32
#define DM   256
#define DF   158
#define GDIM 63
#define XROW 221

typedef unsigned short u16;
typedef __attribute__((ext_vector_type(8))) __bf16 bf16x8;
typedef __attribute__((ext_vector_type(4))) float f32x4;
#define MFMA16(a,b,c) __builtin_amdgcn_mfma_f32_16x16x32_bf16(a,b,c,0,0,0)

#define MODE_QKVT 1
#define MODE_QKVS 2
#define MODE_TEMP 3

__device__ __forceinline__ u16 f2bf(float f){
  union { float f; unsigned int u; } c; c.f = f;
  unsigned int u = c.u;
  u += 0x7fffu + ((u >> 16) & 1u);   // round-to-nearest-even
  return (u16)(u >> 16);
}

// truncating bf16 (for P in attention: bias cancels between O and l)
__device__ __forceinline__ u16 f2bf_t(float f){
  union { float f; unsigned int u; } c; c.f = f;
  return (u16)(c.u >> 16);
}

// async 16B global->LDS DMA: LDS dest = wave-uniform base + lane*16.
__device__ __forceinline__ void gl2lds16(const u16* g, u16* lds_wave_base, int lane){
#if __has_builtin(__builtin_amdgcn_global_load_lds)
  __builtin_amdgcn_global_load_lds(
      (const __attribute__((address_space(1))) unsigned int*)g,
      (__attribute__((address_space(3))) unsigned int*)lds_wave_base,
      16, 0, 0);
#else
  *reinterpret_cast<uint4*>(lds_wave_base + lane * 8) =
      *reinterpret_cast<const uint4*>(g);
#endif
}

// ---------------- weight conversion (fp32 -> bf16, packed) ----------------
#define WB_TOT 770048

__global__ __launch_bounds__(256) void kConvAll(
    const float* __restrict__ tq, const float* __restrict__ tk, const float* __restrict__ tv,
    const float* __restrict__ sq, const float* __restrict__ sk, const float* __restrict__ sv,
    const float* __restrict__ tf1, const float* __restrict__ tf2,
    const float* __restrict__ sf1, const float* __restrict__ sf2,
    const float* __restrict__ tw, const float* __restrict__ pw,
    u16* __restrict__ WB)
{
  int i = blockIdx.x * 256 + threadIdx.x;
  if (i >= WB_TOT) return;
  if (i < 720896){
    int j = i >> 16, o = i & 65535;
    const float* s;
    switch (j){
      case 0: s = tq; break;  case 1: s = tk; break;  case 2: s = tv; break;
      case 3: s = sq; break;  case 4: s = sk; break;  case 5: s = sv; break;
      case 6: s = tf1; break; case 7: s = tf2; break;
      case 8: s = sf1; break; case 9: s = sf2; break;
      default: s = tw; break;
    }
    WB[i] = f2bf(s[o]);
  } else {
    int k = i - 720896;
    int row = k / 192, col = k - row * 192;
    WB[i] = (col < DF) ? f2bf(pw[row * DF + col]) : (u16)0;
  }
}

// ---------------- gate + gated src (bf16, K padded to 192) ----------------

__global__ __launch_bounds__(256) void kGateSrc(
    const float* __restrict__ x,
    const float* __restrict__ gate_w, const float* __restrict__ gate_b,
    u16* __restrict__ SRC)
{
  __shared__ float s_gate[DF];
  __shared__ float s_gi[GDIM];
  const int tid = threadIdx.x;
  const int n = blockIdx.x;

  if (tid < GDIM) s_gi[tid] = x[(n * TSEQ + (TSEQ - 1)) * XROW + DF + tid];
  __syncthreads();
  float logit = 0.f;
  if (tid < DF){
    logit = gate_b[tid];
    const float* __restrict__ wr = gate_w + tid * GDIM;
    for (int g = 0; g < GDIM; ++g) logit += s_gi[g] * wr[g];
    logit *= 0.2f;
    s_gate[tid] = logit;
  }
  __syncthreads();
  {
    float mx = -1e30f;
    for (int f = 0; f < DF; ++f) mx = fmaxf(mx, s_gate[f]);
    float sm = 0.f;
    for (int f = 0; f < DF; ++f) sm += __expf(s_gate[f] - mx);
    __syncthreads();
    if (tid < DF) s_gate[tid] = (float)DF * __expf(logit - mx) / sm;
  }
  __syncthreads();

  for (int e = tid; e < TSEQ * 192; e += 256){
    int t = e / 192, f = e - t * 192;
    float v = 0.f;
    if (f < DF) v = x[(n * TSEQ + t) * XROW + f] * s_gate[f];
    SRC[(size_t)(n * TSEQ + t) * 192 + f] = f2bf(v);
  }
}

// ---------------- fused proj + bias + posenc + LN -> XN (bf16 + fp32) ----------------
// 512 threads, 128 rows x full 256 cols per block (block owns complete rows).

__global__ __launch_bounds__(512) void kProjLN(
    const u16* __restrict__ SRC, const u16* __restrict__ Bw,
    const float* __restrict__ bias,
    const float* __restrict__ lg, const float* __restrict__ lb,
    u16* __restrict__ Xb, float* __restrict__ Xf)
{
  __shared__ alignas(16) u16 sA[128 * 64];   // 16 KB
  __shared__ alignas(16) u16 sB[256 * 64];   // 32 KB
  __shared__ float s_sum[4 * 128], s_sq[4 * 128];
  __shared__ float s_lg[256], s_lb[256], s_bias[256];

  const int tid = threadIdx.x;
  const int wv = tid >> 6, lane = tid & 63;
  const int wr = wv >> 2, wc = wv & 3;
  const int quad = lane >> 4, lc = lane & 15;
  const int m0 = blockIdx.x * 128;

  if (tid < 256){ s_lg[tid] = lg[tid]; s_lb[tid] = lb[tid]; s_bias[tid] = bias[tid]; }

  f32x4 acc[4][4];
  #pragma unroll
  for (int i = 0; i < 4; ++i)
    #pragma unroll
    for (int j = 0; j < 4; ++j) acc[i][j] = (f32x4){0.f,0.f,0.f,0.f};

  for (int kt = 0; kt < 192; kt += 64){
    __syncthreads();
    #pragma unroll
    for (int i = 0; i < 2; ++i){
      int c = tid + i * 512;
      int row = c >> 3, blk = c & 7;
      *reinterpret_cast<uint4*>(&sA[row * 64 + ((blk ^ (row & 7)) * 8)]) =
        *reinterpret_cast<const uint4*>(SRC + (size_t)(m0 + row) * 192 + kt + blk * 8);
    }
    #pragma unroll
    for (int i = 0; i < 4; ++i){
      int c = tid + i * 512;
      int row = c >> 3, blk = c & 7;
      *reinterpret_cast<uint4*>(&sB[row * 64 + ((blk ^ (row & 7)) * 8)]) =
        *reinterpret_cast<const uint4*>(Bw + (size_t)row * 192 + kt + blk * 8);
    }
    __syncthreads();
    #pragma unroll
    for (int kc = 0; kc < 2; ++kc){
      const int sw = ((kc * 4 + quad) ^ (lc & 7)) * 8;
      bf16x8 a[4], b[4];
      #pragma unroll
      for (int i = 0; i < 4; ++i){
        a[i] = *reinterpret_cast<const bf16x8*>(&sA[(wr * 64 + i * 16 + lc) * 64 + sw]);
        b[i] = *reinterpret_cast<const bf16x8*>(&sB[(wc * 64 + i * 16 + lc) * 64 + sw]);
      }
      #pragma unroll
      for (int i = 0; i < 4; ++i)
        #pragma unroll
        for (int j = 0; j < 4; ++j)
          acc[i][j] = MFMA16(a[i], b[j], acc[i][j]);
    }
  }

  // v = proj + bias + posenc (in place), per-row partial sums
  const int rb = wr * 64 + quad * 4;
  #pragma unroll
  for (int i = 0; i < 4; ++i)
    #pragma unroll
    for (int r = 0; r < 4; ++r){
      int rowl = rb + i * 16 + r;
      float ft = (float)((m0 + rowl) & 31);
      float ps = 0.f, pq = 0.f;
      #pragma unroll
      for (int j = 0; j < 4; ++j){
        int col = wc * 64 + j * 16 + lc;
        float div = __expf((float)(col & ~1) * -0.035977892f);
        float ang = ft * div;
        float pe = (col & 1) ? __cosf(ang) : __sinf(ang);
        float v = acc[i][j][r] + s_bias[col] + pe;
        acc[i][j][r] = v;
        ps += v; pq += v * v;
      }
      #pragma unroll
      for (int msk = 1; msk < 16; msk <<= 1){
        ps += __shfl_xor(ps, msk);
        pq += __shfl_xor(pq, msk);
      }
      if (lc == 0){ s_sum[wc * 128 + rowl] = ps; s_sq[wc * 128 + rowl] = pq; }
    }
  __syncthreads();

  #pragma unroll
  for (int i = 0; i < 4; ++i)
    #pragma unroll
    for (int r = 0; r < 4; ++r){
      int rowl = rb + i * 16 + r;
      float sum = s_sum[rowl] + s_sum[128 + rowl] + s_sum[256 + rowl] + s_sum[384 + rowl];
      float sq  = s_sq[rowl]  + s_sq[128 + rowl]  + s_sq[256 + rowl]  + s_sq[384 + rowl];
      float mu = sum * (1.f / 256.f);
      float rs = rsqrtf(sq * (1.f / 256.f) - mu * mu + 1e-5f);
      size_t base = (size_t)(m0 + rowl) * 256;
      #pragma unroll
      for (int j = 0; j < 4; ++j){
        int col = wc * 64 + j * 16 + lc;
        float xn = (acc[i][j][r] - mu) * rs * s_lg[col] + s_lb[col];
        Xf[base + col] = xn;
        Xb[base + col] = f2bf(xn);
      }
    }
}

// ---------------- generic bf16 MFMA GEMM: C = A[M x K] @ B[N x K]^T ----------------
// MODE_QKVS uses a t-major row-block mapping (full-line V^T scatter writes).

__global__ __launch_bounds__(256) void gemm_bf16(
    const u16* __restrict__ A, const u16* __restrict__ B,
    const int K, const int mode,
    float* __restrict__ outf,
    u16* __restrict__ ob0, u16* __restrict__ ob1, u16* __restrict__ ob2)
{
  __shared__ alignas(16) u16 sA[128 * 64];
  __shared__ alignas(16) u16 sB[128 * 64];
  const int tid = threadIdx.x;
  const int wv = tid >> 6, lane = tid & 63;
  const int wr = wv >> 1, wc = wv & 1;
  const int quad = lane >> 4, lc = lane & 15;
  const int n0 = blockIdx.y * 128;
  const bool tmaj = (mode == MODE_QKVS);
  const int tt = tmaj ? (blockIdx.x & 31) : 0;
  const int nb = tmaj ? (blockIdx.x >> 5) : 0;
  const int m0 = tmaj ? 0 : blockIdx.x * 128;

  f32x4 acc[4][4];
  #pragma unroll
  for (int i = 0; i < 4; ++i)
    #pragma unroll
    for (int j = 0; j < 4; ++j) acc[i][j] = (f32x4){0.f,0.f,0.f,0.f};

  for (int kt = 0; kt < K; kt += 64){
    __syncthreads();
    #pragma unroll
    for (int j = 0; j < 4; ++j){
      int c = wv * 64 + lane + j * 256;
      int row = c >> 3, blk = c & 7;
      int arow = tmaj ? ((nb * 128 + row) * 32 + tt) : (m0 + row);
      gl2lds16(A + (size_t)arow * K + kt + ((blk ^ (row & 7)) * 8),
               &sA[(wv * 64 + j * 256) * 8], lane);
      gl2lds16(B + (size_t)(n0 + row) * K + kt + ((blk ^ (row & 7)) * 8),
               &sB[(wv * 64 + j * 256) * 8], lane);
    }
    __syncthreads();
    #pragma unroll
    for (int kc = 0; kc < 2; ++kc){
      const int sw = ((kc * 4 + quad) ^ (lc & 7)) * 8;
      bf16x8 a[4], b[4];
      #pragma unroll
      for (int i = 0; i < 4; ++i){
        a[i] = *reinterpret_cast<const bf16x8*>(&sA[(wr * 64 + i * 16 + lc) * 64 + sw]);
        b[i] = *reinterpret_cast<const bf16x8*>(&sB[(wc * 64 + i * 16 + lc) * 64 + sw]);
      }
      #pragma unroll
      for (int i = 0; i < 4; ++i)
        #pragma unroll
        for (int j = 0; j < 4; ++j)
          acc[i][j] = MFMA16(a[i], b[j], acc[i][j]);
    }
  }

  // -------- epilogue --------
  const int rb = wr * 64 + quad * 4;
  const int cb = wc * 64 + lc;

  if (mode == MODE_QKVT){
    #pragma unroll
    for (int i = 0; i < 4; ++i)
      #pragma unroll
      for (int r = 0; r < 4; ++r){
        int row = m0 + rb + i * 16 + r;
        #pragma unroll
        for (int j = 0; j < 4; ++j){
          int col = n0 + cb + j * 16;
          int sel = col >> 8, c = col & 255;
          u16 v = f2bf(acc[i][j][r]);
          if (sel == 0)      ob0[(size_t)row * 256 + c] = v;
          else if (sel == 1) ob1[(size_t)row * 256 + c] = v;
          else {
            int h = c >> 6, dd = c & 63;
            ob2[(((size_t)(row >> 5) * 4 + h) * 64 + dd) * 32 + (row & 31)] = v;
          }
        }
      }
  } else if (mode == MODE_QKVS){
    #pragma unroll
    for (int i = 0; i < 4; ++i)
      #pragma unroll
      for (int r = 0; r < 4; ++r){
        int rl = rb + i * 16 + r;
        int n = nb * 128 + rl;
        #pragma unroll
        for (int j = 0; j < 4; ++j){
          int col = n0 + cb + j * 16;
          int sel = col >> 8, c = col & 255;
          u16 v = f2bf(acc[i][j][r]);
          if (sel == 0)      ob0[((size_t)tt * NB + n) * 256 + c] = v;
          else if (sel == 1) ob1[((size_t)tt * NB + n) * 256 + c] = v;
          else {
            int h = c >> 7, dd = c & 127;
            ob2[(((size_t)tt * 2 + h) * 128 + dd) * NB + n] = v;
          }
        }
      }
  } else { // MODE_TEMP
    #pragma unroll
    for (int i = 0; i < 4; ++i)
      #pragma unroll
      for (int r = 0; r < 4; ++r){
        int row = m0 + rb + i * 16 + r;
        #pragma unroll
        for (int j = 0; j < 4; ++j){
          int col = n0 + cb + j * 16;
          outf[(size_t)row * 256 + col] = acc[i][j][r];
        }
      }
  }
}

// ---------------- fused LN + FFN (+ optional output-LN) ----------------
// out = ln_in(X) + relu(ln_in(X)@w1^T+b1)@w2^T+b2; if og: emit ln_out(out).

__global__ __launch_bounds__(512) void kFFN(
    const float* __restrict__ X,
    const float* __restrict__ lg, const float* __restrict__ lb,
    const u16* __restrict__ w1, const float* __restrict__ b1,
    const u16* __restrict__ w2, const float* __restrict__ b2,
    const float* __restrict__ og, const float* __restrict__ ob,
    float* __restrict__ outf, u16* __restrict__ obdual)
{
  __shared__ alignas(16) u16 sAB[24576];
  __shared__ alignas(16) u16 s_h1[128 * 256];
  __shared__ float s_mu[128], s_rs[128];
  __shared__ float s_lg[256], s_lb[256], s_b1[256], s_b2[256];
  __shared__ float s_og[256], s_ob[256];
  __shared__ float s_os[2 * 128], s_oq[2 * 128];

  const int tid = threadIdx.x;
  const int wv = tid >> 6, lane = tid & 63;
  const int quad = lane >> 4, lc = lane & 15;
  const int m0 = blockIdx.x * 128;
  const int m0w = (wv >> 1) * 32;
  const int n0w = (wv & 1) * 128;
  u16* sA = sAB;
  u16* sB = sAB + 8192;

  if (tid < 256){
    s_lg[tid] = lg[tid]; s_lb[tid] = lb[tid];
    s_b1[tid] = b1[tid]; s_b2[tid] = b2[tid];
    if (og){ s_og[tid] = og[tid]; s_ob[tid] = ob[tid]; }
  }

  {
    const int row = tid >> 2, j = tid & 3;
    const float4* xr = reinterpret_cast<const float4*>(X + (size_t)(m0 + row) * 256);
    float sum = 0.f, sq = 0.f;
    #pragma unroll
    for (int k = 0; k < 16; ++k){
      float4 v = xr[j + 4 * k];
      sum += v.x + v.y + v.z + v.w;
      sq  += v.x*v.x + v.y*v.y + v.z*v.z + v.w*v.w;
    }
    sum += __shfl_xor(sum, 1); sq += __shfl_xor(sq, 1);
    sum += __shfl_xor(sum, 2); sq += __shfl_xor(sq, 2);
    if (j == 0){
      float mu = sum * (1.f / 256.f);
      s_mu[row] = mu;
      s_rs[row] = rsqrtf(sq * (1.f / 256.f) - mu * mu + 1e-5f);
    }
  }
  __syncthreads();

  f32x4 acc[2][8];
  #pragma unroll
  for (int mt = 0; mt < 2; ++mt)
    #pragma unroll
    for (int j = 0; j < 8; ++j) acc[mt][j] = (f32x4){0.f,0.f,0.f,0.f};

  for (int kt = 0; kt < 4; ++kt){
    __syncthreads();
    {
      const int row = tid >> 2, c0 = (tid & 3) * 16;
      const float mu = s_mu[row], rs = s_rs[row];
      const float* xp = X + (size_t)(m0 + row) * 256 + kt * 64 + c0;
      u16 v16[16];
      #pragma unroll
      for (int k = 0; k < 4; ++k){
        float4 v = *reinterpret_cast<const float4*>(xp + 4 * k);
        int col = kt * 64 + c0 + 4 * k;
        v16[4*k+0] = f2bf((v.x - mu) * rs * s_lg[col+0] + s_lb[col+0]);
        v16[4*k+1] = f2bf((v.y - mu) * rs * s_lg[col+1] + s_lb[col+1]);
        v16[4*k+2] = f2bf((v.z - mu) * rs * s_lg[col+2] + s_lb[col+2]);
        v16[4*k+3] = f2bf((v.w - mu) * rs * s_lg[col+3] + s_lb[col+3]);
      }
      int b0 = c0 >> 3;
      *reinterpret_cast<uint4*>(&sA[row * 64 + ((b0    ) ^ (row & 7)) * 8]) = *reinterpret_cast<uint4*>(&v16[0]);
      *reinterpret_cast<uint4*>(&sA[row * 64 + ((b0 + 1) ^ (row & 7)) * 8]) = *reinterpret_cast<uint4*>(&v16[8]);
    }
    #pragma unroll
    for (int i = 0; i < 4; ++i){
      int c = tid + i * 512;
      int row = c >> 3, blk = c & 7;
      *reinterpret_cast<uint4*>(&sB[row * 64 + (blk ^ (row & 7)) * 8]) =
        *reinterpret_cast<const uint4*>(w1 + (size_t)row * 256 + kt * 64 + blk * 8);
    }
    __syncthreads();
    #pragma unroll
    for (int kc = 0; kc < 2; ++kc){
      const int sw = ((kc * 4 + quad) ^ (lc & 7)) * 8;
      bf16x8 a[2], b[8];
      #pragma unroll
      for (int mt = 0; mt < 2; ++mt)
        a[mt] = *reinterpret_cast<const bf16x8*>(&sA[(m0w + mt * 16 + lc) * 64 + sw]);
      #pragma unroll
      for (int j = 0; j < 8; ++j)
        b[j] = *reinterpret_cast<const bf16x8*>(&sB[(n0w + j * 16 + lc) * 64 + sw]);
      #pragma unroll
      for (int mt = 0; mt < 2; ++mt)
        #pragma unroll
        for (int j = 0; j < 8; ++j)
          acc[mt][j] = MFMA16(a[mt], b[j], acc[mt][j]);
    }
  }
  __syncthreads();

  #pragma unroll
  for (int mt = 0; mt < 2; ++mt)
    #pragma unroll
    for (int r = 0; r < 4; ++r){
      int row = m0w + mt * 16 + quad * 4 + r;
      #pragma unroll
      for (int j = 0; j < 8; ++j){
        int col = n0w + j * 16 + lc;
        u16 v = f2bf(fmaxf(acc[mt][j][r] + s_b1[col], 0.f));
        s_h1[row * 256 + (((col >> 3) ^ (row & 31)) << 3) + (col & 7)] = v;
      }
    }

  #pragma unroll
  for (int mt = 0; mt < 2; ++mt)
    #pragma unroll
    for (int j = 0; j < 8; ++j) acc[mt][j] = (f32x4){0.f,0.f,0.f,0.f};

  for (int kt = 0; kt < 4; ++kt){
    __syncthreads();
    #pragma unroll
    for (int i = 0; i < 4; ++i){
      int c = tid + i * 512;
      int row = c >> 3, blk = c & 7;
      *reinterpret_cast<uint4*>(&sAB[row * 64 + (blk ^ (row & 7)) * 8]) =
        *reinterpret_cast<const uint4*>(w2 + (size_t)row * 256 + kt * 64 + blk * 8);
    }
    __syncthreads();
    #pragma unroll
    for (int kc = 0; kc < 2; ++kc){
      const int sw = ((kc * 4 + quad) ^ (lc & 7)) * 8;
      bf16x8 a[2], b[8];
      #pragma unroll
      for (int mt = 0; mt < 2; ++mt){
        int row = m0w + mt * 16 + lc;
        int cb = kt * 8 + kc * 4 + quad;
        a[mt] = *reinterpret_cast<const bf16x8*>(
            &s_h1[row * 256 + ((cb ^ (row & 31)) << 3)]);
      }
      #pragma unroll
      for (int j = 0; j < 8; ++j)
        b[j] = *reinterpret_cast<const bf16x8*>(&sAB[(n0w + j * 16 + lc) * 64 + sw]);
      #pragma unroll
      for (int mt = 0; mt < 2; ++mt)
        #pragma unroll
        for (int j = 0; j < 8; ++j)
          acc[mt][j] = MFMA16(a[mt], b[j], acc[mt][j]);
    }
  }

  if (og){
    // v in place + per-row partials for output LN
    #pragma unroll
    for (int mt = 0; mt < 2; ++mt)
      #pragma unroll
      for (int r = 0; r < 4; ++r){
        int rowl = m0w + mt * 16 + quad * 4 + r;
        const float mu = s_mu[rowl], rs = s_rs[rowl];
        size_t base = (size_t)(m0 + rowl) * 256;
        float ps = 0.f, pq = 0.f;
        #pragma unroll
        for (int j = 0; j < 8; ++j){
          int col = n0w + j * 16 + lc;
          float xn = (X[base + col] - mu) * rs * s_lg[col] + s_lb[col];
          float v = acc[mt][j][r] + s_b2[col] + xn;
          acc[mt][j][r] = v;
          ps += v; pq += v * v;
        }
        #pragma unroll
        for (int msk = 1; msk < 16; msk <<= 1){
          ps += __shfl_xor(ps, msk);
          pq += __shfl_xor(pq, msk);
        }
        if (lc == 0){
          s_os[(wv & 1) * 128 + rowl] = ps;
          s_oq[(wv & 1) * 128 + rowl] = pq;
        }
      }
    __syncthreads();
    #pragma unroll
    for (int mt = 0; mt < 2; ++mt)
      #pragma unroll
      for (int r = 0; r < 4; ++r){
        int rowl = m0w + mt * 16 + quad * 4 + r;
        float sum = s_os[rowl] + s_os[128 + rowl];
        float sq  = s_oq[rowl] + s_oq[128 + rowl];
        float mu2 = sum * (1.f / 256.f);
        float rs2 = rsqrtf(sq * (1.f / 256.f) - mu2 * mu2 + 1e-5f);
        size_t base = (size_t)(m0 + rowl) * 256;
        #pragma unroll
        for (int j = 0; j < 8; ++j){
          int col = n0w + j * 16 + lc;
          float w = (acc[mt][j][r] - mu2) * rs2 * s_og[col] + s_ob[col];
          outf[base + col] = w;
          obdual[base + col] = f2bf(w);
        }
      }
  } else {
    #pragma unroll
    for (int mt = 0; mt < 2; ++mt)
      #pragma unroll
      for (int r = 0; r < 4; ++r){
        int rowl = m0w + mt * 16 + quad * 4 + r;
        const float mu = s_mu[rowl], rs = s_rs[rowl];
        size_t base = (size_t)(m0 + rowl) * 256;
        #pragma unroll
        for (int j = 0; j < 8; ++j){
          int col = n0w + j * 16 + lc;
          float xn = (X[base + col] - mu) * rs * s_lg[col] + s_lb[col];
          float v = acc[mt][j][r] + s_b2[col] + xn;
          outf[base + col] = v;
          if (obdual) obdual[base + col] = f2bf(v);
        }
      }
  }
}

// ---------------- temporal attention (per-sample, 4 heads, MFMA) ----------------

__global__ __launch_bounds__(256) void kAttnT(
    const u16* __restrict__ Qt, const u16* __restrict__ Kt,
    const u16* __restrict__ VtT, const float* __restrict__ XN1f,
    float* __restrict__ X2)
{
  __shared__ alignas(16) u16 sQ[4][32 * 72];
  __shared__ alignas(16) u16 sK[4][32 * 72];
  __shared__ alignas(16) u16 sV[4][64 * 40];
  __shared__ alignas(16) u16 sP[4][32 * 40];

  const int tid = threadIdx.x;
  const int wv = tid >> 6, lane = tid & 63;
  const int quad = lane >> 4, lc = lane & 15;
  const int n = blockIdx.x;
  const int h = wv;
  const f32x4 zero4 = {0.f, 0.f, 0.f, 0.f};

  #pragma unroll
  for (int i = 0; i < 4; ++i){
    int c = lane + 64 * i;
    int row = c >> 3, blk = c & 7;
    *reinterpret_cast<uint4*>(&sQ[wv][row * 72 + blk * 8]) =
      *reinterpret_cast<const uint4*>(&Qt[((size_t)n * 32 + row) * 256 + h * 64 + blk * 8]);
    *reinterpret_cast<uint4*>(&sK[wv][row * 72 + blk * 8]) =
      *reinterpret_cast<const uint4*>(&Kt[((size_t)n * 32 + row) * 256 + h * 64 + blk * 8]);
    int rv = c >> 2, bv = c & 3;
    *reinterpret_cast<uint4*>(&sV[wv][rv * 40 + bv * 8]) =
      *reinterpret_cast<const uint4*>(&VtT[(((size_t)n * 4 + h) * 64 + rv) * 32 + bv * 8]);
  }
  __syncthreads();

  f32x4 s[2][2];
  #pragma unroll
  for (int mt = 0; mt < 2; ++mt)
    #pragma unroll
    for (int ct = 0; ct < 2; ++ct) s[mt][ct] = zero4;
  #pragma unroll
  for (int kc = 0; kc < 2; ++kc){
    bf16x8 aq[2], bk[2];
    #pragma unroll
    for (int mt = 0; mt < 2; ++mt)
      aq[mt] = *reinterpret_cast<const bf16x8*>(&sQ[wv][(mt * 16 + lc) * 72 + kc * 32 + quad * 8]);
    #pragma unroll
    for (int ct = 0; ct < 2; ++ct)
      bk[ct] = *reinterpret_cast<const bf16x8*>(&sK[wv][(ct * 16 + lc) * 72 + kc * 32 + quad * 8]);
    #pragma unroll
    for (int mt = 0; mt < 2; ++mt)
      #pragma unroll
      for (int ct = 0; ct < 2; ++ct)
        s[mt][ct] = MFMA16(aq[mt], bk[ct], s[mt][ct]);
  }

  #pragma unroll
  for (int mt = 0; mt < 2; ++mt){
    #pragma unroll
    for (int r = 0; r < 4; ++r){
      float v0 = s[mt][0][r], v1 = s[mt][1][r];
      float mx = fmaxf(v0, v1);
      #pragma unroll
      for (int msk = 1; msk < 16; msk <<= 1) mx = fmaxf(mx, __shfl_xor(mx, msk));
      float p0 = __expf(v0 - mx), p1 = __expf(v1 - mx);
      float sm = p0 + p1;
      #pragma unroll
      for (int msk = 1; msk < 16; msk <<= 1) sm += __shfl_xor(sm, msk);
      float inv = 1.f / sm;
      sP[wv][(mt * 16 + quad * 4 + r) * 40 + lc]      = f2bf(p0 * inv);
      sP[wv][(mt * 16 + quad * 4 + r) * 40 + lc + 16] = f2bf(p1 * inv);
    }
  }
  __syncthreads();

  #pragma unroll
  for (int mt = 0; mt < 2; ++mt){
    bf16x8 ap = *reinterpret_cast<const bf16x8*>(&sP[wv][(mt * 16 + lc) * 40 + quad * 8]);
    #pragma unroll
    for (int ct = 0; ct < 4; ++ct){
      bf16x8 bv = *reinterpret_cast<const bf16x8*>(&sV[wv][(ct * 16 + lc) * 40 + quad * 8]);
      f32x4 o = MFMA16(ap, bv, zero4);
      #pragma unroll
      for (int r = 0; r < 4; ++r){
        int t = mt * 16 + quad * 4 + r;
        size_t idx = ((size_t)n * 32 + t) * 256 + h * 64 + ct * 16 + lc;
        X2[idx] = XN1f[idx] + o[r];
      }
    }
  }
}

// ---------------- spatial flash attention (bf16 MFMA, fixed-max, key-split waves) ----

__global__ __launch_bounds__(512) void kB2_flash_mfma(
    const u16* __restrict__ Qh, const u16* __restrict__ Kh,
    const u16* __restrict__ VT, const float* __restrict__ XNs,
    float* __restrict__ XT)
{
  __shared__ alignas(16) u16 smem[28160];   // 55 KB flat
  u16* s_k  = smem;                          // 64*136
  u16* s_vt = smem + 8704;                   // 128*72
  u16* s_p  = smem + 17920;                  // 8 waves * 32*40

  const int tid = threadIdx.x;
  const int wv = tid >> 6, lane = tid & 63;
  const int wq = wv & 3, wk = wv >> 2;
  const int quad = lane >> 4, lc = lane & 15;
  const int t = blockIdx.x >> 1, h = blockIdx.x & 1;
  const int n0 = blockIdx.y * 128;
  const float c_exp2 = 0.12752887f;  // log2(e)/sqrt(128)
  const int qb = n0 + wq * 32;

  bf16x8 qf[2][4];
  #pragma unroll
  for (int mt = 0; mt < 2; ++mt){
    const u16* qp = Qh + ((size_t)(t * NB + qb + mt * 16 + lc)) * DM + h * 128 + quad * 8;
    #pragma unroll
    for (int kc = 0; kc < 4; ++kc)
      qf[mt][kc] = *reinterpret_cast<const bf16x8*>(qp + kc * 32);
  }

  f32x4 o[2][8];
  #pragma unroll
  for (int mt = 0; mt < 2; ++mt)
    #pragma unroll
    for (int f = 0; f < 8; ++f) o[mt][f] = (f32x4){0.f, 0.f, 0.f, 0.f};
  float l_acc[2][4] = {{0.f,0.f,0.f,0.f},{0.f,0.f,0.f,0.f}};

  const u16* kbase  = Kh + (size_t)t * NB * DM + h * 128;
  const u16* vtbase = VT + (size_t)(t * 2 + h) * 128 * NB;
  u16* pw = s_p + wv * 1280;

  for (int j0 = 0; j0 < NB; j0 += 64){
    __syncthreads();
    #pragma unroll
    for (int it = 0; it < 2; ++it){
      int c = tid + it * 512;
      int row = c >> 4, part = c & 15;   // K tile: 64 x 128
      *reinterpret_cast<uint4*>(&s_k[row * 136 + part * 8]) =
        *reinterpret_cast<const uint4*>(kbase + (size_t)(j0 + row) * DM + part * 8);
      int rv = c >> 3, pv = c & 7;       // VT tile: 128 x 64
      *reinterpret_cast<uint4*>(&s_vt[rv * 72 + pv * 8]) =
        *reinterpret_cast<const uint4*>(vtbase + (size_t)rv * NB + j0 + pv * 8);
    }
    __syncthreads();

    f32x4 s[2][2];
    #pragma unroll
    for (int mt = 0; mt < 2; ++mt)
      #pragma unroll
      for (int nt = 0; nt < 2; ++nt) s[mt][nt] = (f32x4){0.f,0.f,0.f,0.f};
    #pragma unroll
    for (int kc = 0; kc < 4; ++kc){
      #pragma unroll
      for (int nt = 0; nt < 2; ++nt){
        bf16x8 bk = *reinterpret_cast<const bf16x8*>(
            &s_k[(lc + 16 * nt + 32 * wk) * 136 + kc * 32 + quad * 8]);
        #pragma unroll
        for (int mt = 0; mt < 2; ++mt)
          s[mt][nt] = MFMA16(qf[mt][kc], bk, s[mt][nt]);
      }
    }

    #pragma unroll
    for (int mt = 0; mt < 2; ++mt)
      #pragma unroll
      for (int nt = 0; nt < 2; ++nt)
        #pragma unroll
        for (int r = 0; r < 4; ++r){
          float p = exp2f(s[mt][nt][r] * c_exp2);
          l_acc[mt][r] += p;
          pw[(mt * 16 + quad * 4 + r) * 40 + lc + 16 * nt] = f2bf_t(p);
        }

    bf16x8 ap[2];
    #pragma unroll
    for (int mt = 0; mt < 2; ++mt)
      ap[mt] = *reinterpret_cast<const bf16x8*>(&pw[(mt * 16 + lc) * 40 + quad * 8]);
    #pragma unroll
    for (int f = 0; f < 8; ++f){
      bf16x8 bv = *reinterpret_cast<const bf16x8*>(
          &s_vt[(lc + 16 * f) * 72 + 32 * wk + quad * 8]);
      #pragma unroll
      for (int mt = 0; mt < 2; ++mt)
        o[mt][f] = MFMA16(ap[mt], bv, o[mt][f]);
    }
  }

  // ---- combine wave pairs (wk=0 keeps, wk=1 contributes) ----
  float* fo = (float*)smem;
  float* fl = (float*)smem + 8192;

  __syncthreads();
  if (wk == 1){
    int base = (wq * 64 + lane) * 32;
    #pragma unroll
    for (int f = 0; f < 8; ++f)
      #pragma unroll
      for (int r = 0; r < 4; ++r) fo[base + f * 4 + r] = o[0][f][r];
    int lb = (wq * 64 + lane) * 8;
    #pragma unroll
    for (int mt = 0; mt < 2; ++mt)
      #pragma unroll
      for (int r = 0; r < 4; ++r) fl[lb + mt * 4 + r] = l_acc[mt][r];
  }
  __syncthreads();
  if (wk == 0){
    int base = (wq * 64 + lane) * 32;
    #pragma unroll
    for (int f = 0; f < 8; ++f)
      #pragma unroll
      for (int r = 0; r < 4; ++r) o[0][f][r] += fo[base + f * 4 + r];
    int lb = (wq * 64 + lane) * 8;
    #pragma unroll
    for (int mt = 0; mt < 2; ++mt)
      #pragma unroll
      for (int r = 0; r < 4; ++r){
        l_acc[mt][r] += fl[lb + mt * 4 + r];
        #pragma unroll
        for (int msk = 1; msk < 16; msk <<= 1)
          l_acc[mt][r] += __shfl_xor(l_acc[mt][r], msk);
      }
    #pragma unroll
    for (int r = 0; r < 4; ++r){
      float linv = 1.f / l_acc[0][r];
      int row = qb + quad * 4 + r;
      size_t xnb = ((size_t)row * TSEQ + t) * DM + h * 128 + lc;
      size_t xtb = ((size_t)t * NB + row) * DM + h * 128 + lc;
      #pragma unroll
      for (int f = 0; f < 8; ++f)
        XT[xtb + f * 16] = XNs[xnb + f * 16] + o[0][f][r] * linv;
    }
  }
  __syncthreads();
  if (wk == 1){
    int base = (wq * 64 + lane) * 32;
    #pragma unroll
    for (int f = 0; f < 8; ++f)
      #pragma unroll
      for (int r = 0; r < 4; ++r) fo[base + f * 4 + r] = o[1][f][r];
  }
  __syncthreads();
  if (wk == 0){
    int base = (wq * 64 + lane) * 32;
    #pragma unroll
    for (int f = 0; f < 8; ++f)
      #pragma unroll
      for (int r = 0; r < 4; ++r) o[1][f][r] += fo[base + f * 4 + r];
    #pragma unroll
    for (int r = 0; r < 4; ++r){
      float linv = 1.f / l_acc[1][r];
      int row = qb + 16 + quad * 4 + r;
      size_t xnb = ((size_t)row * TSEQ + t) * DM + h * 128 + lc;
      size_t xtb = ((size_t)t * NB + row) * DM + h * 128 + lc;
      #pragma unroll
      for (int f = 0; f < 8; ++f)
        XT[xtb + f * 16] = XNs[xnb + f * 16] + o[1][f][r] * linv;
    }
  }
}

// ---------------- pooling + output head ----------------

__global__ __launch_bounds__(256) void kC_pool(
    const float* __restrict__ Ht, const float* __restrict__ ZS,
    const float* __restrict__ out_w, const float* __restrict__ out_b,
    float* __restrict__ out)
{
  __shared__ float s_z[32 * DM];
  __shared__ float s_h[32 * 260];
  __shared__ float s_sc[32];
  __shared__ float s_red[4];
  const int tid = threadIdx.x;
  const int n = blockIdx.x;

  for (int e = tid; e < 32 * DM; e += 256){
    int i = e >> 8, dd = e & 255;
    s_h[i * 260 + dd] = Ht[((size_t)i * NB + n) * DM + dd];
    s_z[e]            = ZS[((size_t)i * NB + n) * DM + dd];
  }
  __syncthreads();

  {
    const int s = tid >> 3, j = tid & 7;
    float acc = 0.f;
    #pragma unroll
    for (int k = 0; k < DM; k += 8) acc += s_h[s * 260 + k + j] * s_h[31 * 260 + k + j];
    #pragma unroll
    for (int o = 1; o < 8; o <<= 1) acc += __shfl_xor(acc, o);
    if (j == 0) s_sc[s] = acc;
  }
  __syncthreads();

  float mx = -1e30f;
  #pragma unroll
  for (int s = 0; s < 32; ++s) mx = fmaxf(mx, s_sc[s]);
  float sm = 0.f;
  #pragma unroll
  for (int s = 0; s < 32; ++s) sm += __expf(s_sc[s] - mx);
  const float inv = 1.f / sm;

  const int d = tid;
  float pooled = 0.f;
  #pragma unroll
  for (int s = 0; s < 32; ++s) pooled += __expf(s_sc[s] - mx) * inv * s_z[s * DM + d];

  float val = pooled * out_w[d];
  #pragma unroll
  for (int o = 1; o < 64; o <<= 1) val += __shfl_xor(val, o);
  if ((tid & 63) == 0) s_red[tid >> 6] = val;
  __syncthreads();
  if (tid == 0) out[n] = s_red[0] + s_red[1] + s_red[2] + s_red[3] + out_b[0];
}

// ---------------- launch ----------------

extern "C" void kernel_launch(void* const* d_in, const int* in_sizes, int n_in,
                              void* d_out, int out_size, void* d_ws, size_t ws_size,
                              hipStream_t stream)
{
  const float* x      = (const float*)d_in[0];
  const float* gate_w = (const float*)d_in[1];
  const float* gate_b = (const float*)d_in[2];
  const float* proj_w = (const float*)d_in[3];
  const float* proj_b = (const float*)d_in[4];
  const float* tq   = (const float*)d_in[5];
  const float* tk   = (const float*)d_in[6];
  const float* tv   = (const float*)d_in[7];
  const float* tn1g = (const float*)d_in[8];
  const float* tn1b = (const float*)d_in[9];
  const float* tn2g = (const float*)d_in[10];
  const float* tn2b = (const float*)d_in[11];
  const float* tf1w = (const float*)d_in[12];
  const float* tf1b = (const float*)d_in[13];
  const float* tf2w = (const float*)d_in[14];
  const float* tf2b = (const float*)d_in[15];
  const float* sq   = (const float*)d_in[16];
  const float* sk   = (const float*)d_in[17];
  const float* sv   = (const float*)d_in[18];
  const float* sn1g = (const float*)d_in[19];
  const float* sn1b = (const float*)d_in[20];
  const float* sn2g = (const float*)d_in[21];
  const float* sn2b = (const float*)d_in[22];
  const float* sf1w = (const float*)d_in[23];
  const float* sf1b = (const float*)d_in[24];
  const float* sf2w = (const float*)d_in[25];
  const float* sf2b = (const float*)d_in[26];
  const float* temp_w = (const float*)d_in[27];
  const float* out_w  = (const float*)d_in[28];
  const float* out_b  = (const float*)d_in[29];

  float* W = (float*)d_ws;
  const size_t F = (size_t)NB * TSEQ * DM;  // 8,388,608

  float* Z  = W;                  // X2 / XT / ZS  (fp32)
  float* XF = W + F;              // XN1f / XS1f / Ht
  u16* U0 = (u16*)(W + 2 * F);        // XN1b / VTs / ZSb
  u16* U1 = (u16*)(W + 2 * F) + F;    // Qt / Ks
  u16* U2 = (u16*)(W + 3 * F);        // Kt / XS1b
  u16* U3 = (u16*)(W + 3 * F) + F;    // VtT / Qs
  u16* SRC = (u16*)(W + 4 * F);       // 32768*192 bf16
  u16* WB  = (u16*)(W + 4 * F + 3145728 + 4096);

  kConvAll<<<(WB_TOT + 255) / 256, 256, 0, stream>>>(
      tq, tk, tv, sq, sk, sv, tf1w, tf2w, sf1w, sf2w, temp_w, proj_w, WB);
  kGateSrc<<<NB, 256, 0, stream>>>(x, gate_w, gate_b, SRC);
  // proj + bias + posenc + LN1 -> XN (bf16 U0, fp32 XF); Z never materialized
  kProjLN<<<256, 512, 0, stream>>>(SRC, WB + 720896, proj_b, tn1g, tn1b, U0, XF);
  gemm_bf16<<<dim3(256, 6), 256, 0, stream>>>(U0, WB, 256, MODE_QKVT,
      nullptr, U1, U2, U3);
  kAttnT<<<NB, 256, 0, stream>>>(U1, U2, U3, XF, Z);
  // temporal LN2+FFN, with fused OUTPUT LN (spatial LN1) -> XS1 (fp32 XF, bf16 U2)
  kFFN<<<256, 512, 0, stream>>>(Z, tn2g, tn2b, WB + 393216, tf1b,
      WB + 458752, tf2b, sn1g, sn1b, XF, U2);
  gemm_bf16<<<dim3(256, 6), 256, 0, stream>>>(U2, WB + 196608, 256, MODE_QKVS,
      nullptr, U3, U1, U0);
  kB2_flash_mfma<<<dim3(64, 8), 512, 0, stream>>>(U3, U1, U0, XF, Z);
  // spatial LN2+FFN (plain output): ZS fp32 Z + bf16 U0
  kFFN<<<256, 512, 0, stream>>>(Z, sn2g, sn2b, WB + 524288, sf1b,
      WB + 589824, sf2b, nullptr, nullptr, Z, U0);
  gemm_bf16<<<dim3(256, 2), 256, 0, stream>>>(U0, WB + 655360, 256, MODE_TEMP,
      XF, nullptr, nullptr, nullptr);
  kC_pool<<<NB, 256, 0, stream>>>(XF, Z, out_w, out_b, (float*)d_out);
}